// Round 7
// baseline (474.173 us; speedup 1.0000x reference)
//
#include <hip/hip_runtime.h>
#include <hip/hip_bf16.h>
#include <hip/hip_fp16.h>
#include <math.h>

#define N_NODES 100000
#define N_EDGES 3200000
#define ET (N_EDGES + N_NODES)
#define F_IN 128
#define HID 32
#define NCLS 40
#define NEG 0.2f

// bucket sort geometry
#define NB 782
#define NBLK 782
#define CHUNK 4096
#define BCAP 6144

// ---------------- Pass A: bucket histogram ----------------
__global__ __launch_bounds__(256) void kA_hist(const int* __restrict__ dst,
                                               int* __restrict__ Hm) {
    __shared__ int hist[NB];
    int t = threadIdx.x, k = blockIdx.x;
    for (int i = t; i < NB; i += 256) hist[i] = 0;
    __syncthreads();
    int base = k * CHUNK;
#pragma unroll
    for (int j = 0; j < CHUNK / 256; j++) {
        int e = base + j * 256 + t;
        if (e < N_EDGES) atomicAdd(&hist[dst[e] >> 7], 1);
    }
    __syncthreads();
    for (int i = t; i < NB; i += 256) Hm[i * NBLK + k] = hist[i];
}

// ---------------- generic exclusive scan ----------------
__global__ void k_scan_a(const int* __restrict__ in, int* __restrict__ out,
                         int* __restrict__ bsums, int L) {
    __shared__ int sd[256];
    int t = threadIdx.x, b = blockIdx.x;
    int base = b * 1024 + t * 4;
    int v0 = 0, v1 = 0, v2 = 0, v3 = 0;
    if (base     < L) v0 = in[base];
    if (base + 1 < L) v1 = in[base + 1];
    if (base + 2 < L) v2 = in[base + 2];
    if (base + 3 < L) v3 = in[base + 3];
    int ts = v0 + v1 + v2 + v3;
    sd[t] = ts;
    __syncthreads();
    for (int off = 1; off < 256; off <<= 1) {
        int xx = (t >= off) ? sd[t - off] : 0;
        __syncthreads();
        sd[t] += xx;
        __syncthreads();
    }
    int ex = sd[t] - ts;
    if (t == 255) bsums[b] = sd[255];
    if (base     < L) out[base]     = ex;
    if (base + 1 < L) out[base + 1] = ex + v0;
    if (base + 2 < L) out[base + 2] = ex + v0 + v1;
    if (base + 3 < L) out[base + 3] = ex + v0 + v1 + v2;
}

__global__ void k_scan_b(const int* __restrict__ bsums, int* __restrict__ boffs, int nb) {
    __shared__ int sd[256];
    int t = threadIdx.x;
    int base = t * 4;
    int v0 = 0, v1 = 0, v2 = 0, v3 = 0;
    if (base     < nb) v0 = bsums[base];
    if (base + 1 < nb) v1 = bsums[base + 1];
    if (base + 2 < nb) v2 = bsums[base + 2];
    if (base + 3 < nb) v3 = bsums[base + 3];
    int ts = v0 + v1 + v2 + v3;
    sd[t] = ts;
    __syncthreads();
    for (int off = 1; off < 256; off <<= 1) {
        int xx = (t >= off) ? sd[t - off] : 0;
        __syncthreads();
        sd[t] += xx;
        __syncthreads();
    }
    int ex = sd[t] - ts;
    if (base     < nb) boffs[base]     = ex;
    if (base + 1 < nb) boffs[base + 1] = ex + v0;
    if (base + 2 < nb) boffs[base + 2] = ex + v0 + v1;
    if (base + 3 < nb) boffs[base + 3] = ex + v0 + v1 + v2;
}

__global__ void k_scan_c(int* __restrict__ out, const int* __restrict__ boffs, int L) {
    int i = blockIdx.x * 256 + threadIdx.x;
    if (i < L) out[i] += boffs[i >> 10];
}

// ---------------- Pass A: scatter into buckets ----------------
__global__ __launch_bounds__(256) void kA_scatter(
    const int* __restrict__ src, const int* __restrict__ dst,
    const int* __restrict__ Sx, unsigned int* __restrict__ tmp) {
    __shared__ int hist[NB];
    __shared__ int lofs[NB];
    __shared__ int cur[NB];
    __shared__ int tsum[256];
    __shared__ unsigned int stage[CHUNK];
    __shared__ int gpos[CHUNK];
    int t = threadIdx.x, k = blockIdx.x;
    for (int i = t; i < NB; i += 256) hist[i] = 0;
    __syncthreads();
    int base = k * CHUNK;
    int myd[16], mys[16];
#pragma unroll
    for (int j = 0; j < 16; j++) {
        int e = base + j * 256 + t;
        myd[j] = (e < N_EDGES) ? dst[e] : -1;
        mys[j] = (e < N_EDGES) ? src[e] : 0;
        if (myd[j] >= 0) atomicAdd(&hist[myd[j] >> 7], 1);
    }
    __syncthreads();
    int i0 = 4 * t;
    int h0 = (i0     < NB) ? hist[i0]     : 0;
    int h1 = (i0 + 1 < NB) ? hist[i0 + 1] : 0;
    int h2 = (i0 + 2 < NB) ? hist[i0 + 2] : 0;
    int h3 = (i0 + 3 < NB) ? hist[i0 + 3] : 0;
    int ts = h0 + h1 + h2 + h3;
    tsum[t] = ts;
    __syncthreads();
    for (int off = 1; off < 256; off <<= 1) {
        int xx = (t >= off) ? tsum[t - off] : 0;
        __syncthreads();
        tsum[t] += xx;
        __syncthreads();
    }
    int ex = tsum[t] - ts;
    if (i0     < NB) { lofs[i0]     = ex;                cur[i0]     = 0; }
    if (i0 + 1 < NB) { lofs[i0 + 1] = ex + h0;           cur[i0 + 1] = 0; }
    if (i0 + 2 < NB) { lofs[i0 + 2] = ex + h0 + h1;      cur[i0 + 2] = 0; }
    if (i0 + 3 < NB) { lofs[i0 + 3] = ex + h0 + h1 + h2; cur[i0 + 3] = 0; }
    __syncthreads();
#pragma unroll
    for (int j = 0; j < 16; j++) {
        if (myd[j] >= 0) {
            int bkt = myd[j] >> 7;
            int slot = lofs[bkt] + atomicAdd(&cur[bkt], 1);
            stage[slot] = ((unsigned int)(myd[j] & 127) << 17) | (unsigned int)mys[j];
            gpos[slot] = Sx[bkt * NBLK + k] + (slot - lofs[bkt]);
        }
    }
    __syncthreads();
    int nvalid = min(CHUNK, N_EDGES - base);
    for (int i = t; i < nvalid; i += 256) tmp[gpos[i]] = stage[i];
}

// ---------------- Pass B: per-bucket counting sort ----------------
__global__ __launch_bounds__(256) void kB_sort(
    const unsigned int* __restrict__ tmp, const int* __restrict__ Sx,
    int* __restrict__ esrc, int* __restrict__ rs, int* __restrict__ deg) {
    __shared__ unsigned int stage[BCAP];
    __shared__ int ordered[BCAP + 128];
    __shared__ int cnt[128], lofs[128], cur[128], sc[128];
    int t = threadIdx.x, b = blockIdx.x;
    int myBase = Sx[b * NBLK];
    int nextBase = (b == NB - 1) ? N_EDGES : Sx[(b + 1) * NBLK];
    int cntE = nextBase - myBase;
    int nNodes = min(128, N_NODES - b * 128);
    if (t < 128) { cnt[t] = 0; cur[t] = 0; }
    __syncthreads();
    for (int i = t; i < cntE; i += 256) {
        unsigned int p = tmp[myBase + i];
        stage[i] = p;
        atomicAdd(&cnt[p >> 17], 1);
    }
    __syncthreads();
    int val = 0;
    if (t < 128) { val = (t < nNodes) ? cnt[t] + 1 : 0; sc[t] = val; }
    __syncthreads();
    for (int off = 1; off < 128; off <<= 1) {
        int xx = 0;
        if (t < 128 && t >= off) xx = sc[t - off];
        __syncthreads();
        if (t < 128) sc[t] += xx;
        __syncthreads();
    }
    if (t < 128) lofs[t] = sc[t] - val;
    __syncthreads();
    if (t < nNodes) ordered[lofs[t]] = b * 128 + t;
    for (int i = t; i < cntE; i += 256) {
        unsigned int p = stage[i];
        int n = p >> 17;
        int slot = lofs[n] + 1 + atomicAdd(&cur[n], 1);
        ordered[slot] = (int)(p & 0x1FFFF);
    }
    __syncthreads();
    int gb = myBase + b * 128;
    int totOut = cntE + nNodes;
    for (int i = t; i < totOut; i += 256) esrc[gb + i] = ordered[i];
    if (t < nNodes) {
        rs[b * 128 + t] = gb + lofs[t];
        deg[b * 128 + t] = cnt[t] + 1;
    }
}

// ---------------- prep: va_s = W2 @ att_src2, va_d = W2 @ att_dst2 ----------------
__global__ void k_prep(const float* __restrict__ W2, const float* __restrict__ as2,
                       const float* __restrict__ ad2,
                       float* __restrict__ va_s, float* __restrict__ va_d) {
    int k = threadIdx.x;
    if (k < HID) {
        float ps = 0.f, pd = 0.f;
        for (int c = 0; c < NCLS; c++) {
            float w = W2[k * NCLS + c];
            ps = fmaf(w, as2[c], ps);
            pd = fmaf(w, ad2[c], pd);
        }
        va_s[k] = ps;
        va_d[k] = pd;
    }
}

// ---------------- GEMM1: h1 split fp16 tables (16+16 ch) ; s1,d1 fp32 ----------------
__global__ __launch_bounds__(256) void k_gemm1(
    const float* __restrict__ x, const float* __restrict__ W1,
    const float* __restrict__ a_s, const float* __restrict__ a_d,
    __half* __restrict__ h1A, __half* __restrict__ h1B,
    float* __restrict__ s1, float* __restrict__ d1) {
    __shared__ float Ws[F_IN * HID];
    __shared__ float xs[8 * F_IN];
    int t = threadIdx.x;
    const float4* W4 = (const float4*)W1;
    float4* Ws4 = (float4*)Ws;
#pragma unroll
    for (int i = 0; i < F_IN * HID / 4 / 256; i++)
        Ws4[t + i * 256] = W4[t + i * 256];
    ((float4*)xs)[t] = ((const float4*)(x + (size_t)blockIdx.x * 8 * F_IN))[t];
    __syncthreads();
    int c = t & 31, g = t >> 5;
    int v = blockIdx.x * 8 + g;
    const float4* xg4 = (const float4*)(xs + g * F_IN);
    float acc = 0.f;
#pragma unroll
    for (int k4 = 0; k4 < F_IN / 4; k4++) {
        float4 xv = xg4[k4];
        int k = k4 * 4;
        acc = fmaf(xv.x, Ws[(k + 0) * HID + c], acc);
        acc = fmaf(xv.y, Ws[(k + 1) * HID + c], acc);
        acc = fmaf(xv.z, Ws[(k + 2) * HID + c], acc);
        acc = fmaf(xv.w, Ws[(k + 3) * HID + c], acc);
    }
    if (c < 16) h1A[(size_t)v * 16 + c]        = __float2half(acc);
    else        h1B[(size_t)v * 16 + (c - 16)] = __float2half(acc);
    float p = acc * a_s[c];
    float q = acc * a_d[c];
    for (int mm = 16; mm >= 1; mm >>= 1) {
        p += __shfl_xor(p, mm, 32);
        q += __shfl_xor(q, mm, 32);
    }
    if (c == 0) { s1[v] = p; d1[v] = q; }
}

// ---------------- stats: single pass, unnormalized fp16 weights + 1/den ----------------
__global__ __launch_bounds__(256) void k_stats(
    const int* __restrict__ rs, const int* __restrict__ deg, const int* __restrict__ esrc,
    const float* __restrict__ sarr, const float* __restrict__ darr,
    __half* __restrict__ wout, float* __restrict__ idenS) {
    int lane = threadIdx.x & 63;
    int v = blockIdx.x * 4 + (threadIdx.x >> 6);
    int start = rs[v];
    int cnt = deg[v];
    float dval = darr[v];
    float den = 0.f;
    for (int t = lane; t < cnt; t += 64) {
        int s = esrc[start + t];
        float e = sarr[s] + dval;
        e = (e >= 0.f) ? e : NEG * e;
        float w = __expf(e);   // logits O(+-7): exp safe, no max shift needed
        wout[start + t] = __float2half(w);
        den += w;
    }
    for (int off = 32; off >= 1; off >>= 1) den += __shfl_xor(den, off);
    if (lane == 0) idenS[v] = 1.f / den;
}

// ---------------- generic gather pass A: 16-ch half-table -> partial fp32 ----------------
// wave/node; 8 half2-lanes per edge, 8 edge slots, 2-deep unroll (16 chains)
__global__ __launch_bounds__(256) void k_agg_pass(
    const int* __restrict__ rs, const int* __restrict__ deg, const int* __restrict__ esrc,
    const __half2* __restrict__ tab, const __half* __restrict__ wbuf,
    float2* __restrict__ pA) {
    int lane = threadIdx.x & 63;
    int v = blockIdx.x * 4 + (threadIdx.x >> 6);
    int c2 = lane & 7;
    int esub = lane >> 3;  // 0..7
    int start = rs[v];
    int cnt = deg[v];
    float ax = 0.f, ay = 0.f;
    int t = esub;
    for (; t + 8 < cnt; t += 16) {
        int p = start + t;
        int sa = esrc[p];
        int sb = esrc[p + 8];
        float wa = __half2float(wbuf[p]);
        float wb = __half2float(wbuf[p + 8]);
        float2 fa = __half22float2(tab[sa * 8 + c2]);
        float2 fb = __half22float2(tab[sb * 8 + c2]);
        ax = fmaf(wa, fa.x, ax); ay = fmaf(wa, fa.y, ay);
        ax = fmaf(wb, fb.x, ax); ay = fmaf(wb, fb.y, ay);
    }
    for (; t < cnt; t += 8) {
        int p = start + t;
        int sa = esrc[p];
        float wa = __half2float(wbuf[p]);
        float2 fa = __half22float2(tab[sa * 8 + c2]);
        ax = fmaf(wa, fa.x, ax);
        ay = fmaf(wa, fa.y, ay);
    }
    ax += __shfl_xor(ax, 8);  ay += __shfl_xor(ay, 8);
    ax += __shfl_xor(ax, 16); ay += __shfl_xor(ay, 16);
    ax += __shfl_xor(ax, 32); ay += __shfl_xor(ay, 32);
    if (esub == 0) {
        float2 o; o.x = ax; o.y = ay;
        pA[v * 8 + c2] = o;
    }
}

// ---------------- agg1 pass B: gather h1B + combine pA -> hrtA/hrtB + fused s2,d2 ----
__global__ __launch_bounds__(256) void k_agg1b(
    const int* __restrict__ rs, const int* __restrict__ deg, const int* __restrict__ esrc,
    const __half2* __restrict__ tab, const __half* __restrict__ wbuf,
    const float2* __restrict__ pA, const float* __restrict__ idenS,
    const float* __restrict__ b1, const float* __restrict__ va_s, const float* __restrict__ va_d,
    __half2* __restrict__ hrtA, __half2* __restrict__ hrtB,
    float* __restrict__ s2, float* __restrict__ d2) {
    int lane = threadIdx.x & 63;
    int v = blockIdx.x * 4 + (threadIdx.x >> 6);
    int c2 = lane & 7;
    int esub = lane >> 3;
    int start = rs[v];
    int cnt = deg[v];
    float ax = 0.f, ay = 0.f;
    int t = esub;
    for (; t + 8 < cnt; t += 16) {
        int p = start + t;
        int sa = esrc[p];
        int sb = esrc[p + 8];
        float wa = __half2float(wbuf[p]);
        float wb = __half2float(wbuf[p + 8]);
        float2 fa = __half22float2(tab[sa * 8 + c2]);
        float2 fb = __half22float2(tab[sb * 8 + c2]);
        ax = fmaf(wa, fa.x, ax); ay = fmaf(wa, fa.y, ay);
        ax = fmaf(wb, fb.x, ax); ay = fmaf(wb, fb.y, ay);
    }
    for (; t < cnt; t += 8) {
        int p = start + t;
        int sa = esrc[p];
        float wa = __half2float(wbuf[p]);
        float2 fa = __half22float2(tab[sa * 8 + c2]);
        ax = fmaf(wa, fa.x, ax);
        ay = fmaf(wa, fa.y, ay);
    }
    ax += __shfl_xor(ax, 8);  ay += __shfl_xor(ay, 8);
    ax += __shfl_xor(ax, 16); ay += __shfl_xor(ay, 16);
    ax += __shfl_xor(ax, 32); ay += __shfl_xor(ay, 32);
    float p_ = 0.f, q_ = 0.f;
    if (esub == 0) {
        float iden = idenS[v];
        float2 pa = pA[v * 8 + c2];
        // channels 2c2, 2c2+1 (half A) and 16+2c2, 16+2c2+1 (half B)
        float o0 = fmaxf(pa.x * iden + b1[2 * c2], 0.f);
        float o1 = fmaxf(pa.y * iden + b1[2 * c2 + 1], 0.f);
        float o2 = fmaxf(ax * iden + b1[16 + 2 * c2], 0.f);
        float o3 = fmaxf(ay * iden + b1[16 + 2 * c2 + 1], 0.f);
        hrtA[v * 8 + c2] = __floats2half2_rn(o0, o1);
        hrtB[v * 8 + c2] = __floats2half2_rn(o2, o3);
        p_ = o0 * va_s[2 * c2] + o1 * va_s[2 * c2 + 1]
           + o2 * va_s[16 + 2 * c2] + o3 * va_s[16 + 2 * c2 + 1];
        q_ = o0 * va_d[2 * c2] + o1 * va_d[2 * c2 + 1]
           + o2 * va_d[16 + 2 * c2] + o3 * va_d[16 + 2 * c2 + 1];
        p_ += __shfl_xor(p_, 1); q_ += __shfl_xor(q_, 1);
        p_ += __shfl_xor(p_, 2); q_ += __shfl_xor(q_, 2);
        p_ += __shfl_xor(p_, 4); q_ += __shfl_xor(q_, 4);
        if (c2 == 0) { s2[v] = p_; d2[v] = q_; }
    }
}

// ---------------- agg2 pass B: gather hrtB + combine pA -> @W2 + log_softmax ----------
__global__ __launch_bounds__(256) void k_agg2b(
    const int* __restrict__ rs, const int* __restrict__ deg, const int* __restrict__ esrc,
    const __half2* __restrict__ tab, const __half* __restrict__ wbuf,
    const float2* __restrict__ pA, const float* __restrict__ idenS,
    const float* __restrict__ W2, const float* __restrict__ b2,
    float* __restrict__ out) {
    __shared__ float W2s[HID * NCLS];   // 5 KB
    __shared__ float hragg[4][HID];
    int tid = threadIdx.x;
    for (int i = tid; i < HID * NCLS; i += 256) W2s[i] = W2[i];
    __syncthreads();
    int lane = tid & 63;
    int wid = tid >> 6;
    int v = blockIdx.x * 4 + wid;
    int c2 = lane & 7;
    int esub = lane >> 3;
    int start = rs[v];
    int cnt = deg[v];
    float ax = 0.f, ay = 0.f;
    int t = esub;
    for (; t + 8 < cnt; t += 16) {
        int p = start + t;
        int sa = esrc[p];
        int sb = esrc[p + 8];
        float wa = __half2float(wbuf[p]);
        float wb = __half2float(wbuf[p + 8]);
        float2 fa = __half22float2(tab[sa * 8 + c2]);
        float2 fb = __half22float2(tab[sb * 8 + c2]);
        ax = fmaf(wa, fa.x, ax); ay = fmaf(wa, fa.y, ay);
        ax = fmaf(wb, fb.x, ax); ay = fmaf(wb, fb.y, ay);
    }
    for (; t < cnt; t += 8) {
        int p = start + t;
        int sa = esrc[p];
        float wa = __half2float(wbuf[p]);
        float2 fa = __half22float2(tab[sa * 8 + c2]);
        ax = fmaf(wa, fa.x, ax);
        ay = fmaf(wa, fa.y, ay);
    }
    ax += __shfl_xor(ax, 8);  ay += __shfl_xor(ay, 8);
    ax += __shfl_xor(ax, 16); ay += __shfl_xor(ay, 16);
    ax += __shfl_xor(ax, 32); ay += __shfl_xor(ay, 32);
    if (esub == 0) {
        float iden = idenS[v];
        float2 pa = pA[v * 8 + c2];
        hragg[wid][2 * c2]          = pa.x * iden;
        hragg[wid][2 * c2 + 1]      = pa.y * iden;
        hragg[wid][16 + 2 * c2]     = ax * iden;
        hragg[wid][16 + 2 * c2 + 1] = ay * iden;
    }
    __syncthreads();
    // epilogue: z = hragg @ W2 + b2 ; relu ; log_softmax over 40 classes
    float z = 0.f;
    if (lane < NCLS) {
#pragma unroll
        for (int k = 0; k < HID; k++)
            z = fmaf(hragg[wid][k], W2s[k * NCLS + lane], z);
        z = fmaxf(z + b2[lane], 0.f);
    }
    float mz = (lane < NCLS) ? z : -INFINITY;
    for (int mm = 32; mm >= 1; mm >>= 1) mz = fmaxf(mz, __shfl_xor(mz, mm));
    float ex = (lane < NCLS) ? __expf(z - mz) : 0.f;
    float se = ex;
    for (int mm = 32; mm >= 1; mm >>= 1) se += __shfl_xor(se, mm);
    if (lane < NCLS) out[(size_t)v * NCLS + lane] = z - mz - logf(se);
}

// ---------------- launch ----------------

extern "C" void kernel_launch(void* const* d_in, const int* in_sizes, int n_in,
                              void* d_out, int out_size, void* d_ws, size_t ws_size,
                              hipStream_t stream) {
    (void)in_sizes; (void)n_in; (void)out_size; (void)ws_size;
    const float* x   = (const float*)d_in[0];
    const int*   ei  = (const int*)d_in[1];
    const float* W1  = (const float*)d_in[2];
    const float* as1 = (const float*)d_in[3];
    const float* ad1 = (const float*)d_in[4];
    const float* b1  = (const float*)d_in[5];
    const float* W2  = (const float*)d_in[6];
    const float* as2 = (const float*)d_in[7];
    const float* ad2 = (const float*)d_in[8];
    const float* b2  = (const float*)d_in[9];
    float* out = (float*)d_out;
    const int* srcA = ei;
    const int* dstA = ei + N_EDGES;

    char* w = (char*)d_ws;
    size_t off = 0;
    auto alloc = [&](size_t bytes) {
        char* p = w + off;
        off = (off + bytes + 255) & ~(size_t)255;
        return p;
    };
    int* esrc     = (int*)alloc((size_t)ET * 4);
    int* rs       = (int*)alloc((size_t)N_NODES * 4);
    int* deg      = (int*)alloc((size_t)N_NODES * 4);
    char* region1 = alloc((size_t)N_NODES * HID * 4);   // Hm/Sx during build, then h1A/h1B
    float* s1     = (float*)alloc((size_t)N_NODES * 4);
    float* d1     = (float*)alloc((size_t)N_NODES * 4);
    __half* hrtA  = (__half*)alloc((size_t)N_NODES * 16 * 2);  // hr cols 0-15  (3.2 MB)
    __half* hrtB  = (__half*)alloc((size_t)N_NODES * 16 * 2);  // hr cols 16-31 (3.2 MB)
    char* region2 = alloc((size_t)N_EDGES * 4 + 1024);  // tmp (build), then pA partials
    float* s2     = (float*)alloc((size_t)N_NODES * 4);
    float* d2     = (float*)alloc((size_t)N_NODES * 4);
    __half* wbuf  = (__half*)alloc((size_t)ET * 2);     // per-edge weights fp16
    float* idenS  = (float*)alloc((size_t)N_NODES * 4);
    float* va_s   = (float*)alloc(HID * 4);
    float* va_d   = (float*)alloc(HID * 4);
    int* bsums    = (int*)alloc(1024 * 4);
    int* boffs    = (int*)alloc(1024 * 4);

    const int L = NB * NBLK;
    int* Hm = (int*)region1;
    int* Sx = Hm + ((L + 63) & ~63);
    __half* h1A = (__half*)region1;                            // 3.2 MB
    __half* h1B = (__half*)(region1 + (size_t)N_NODES * 16 * 2); // 3.2 MB
    unsigned int* tmp = (unsigned int*)region2;
    float2* pA = (float2*)region2;                             // 6.4 MB (after build)

    int nb1 = (L + 1023) / 1024;
    hipLaunchKernelGGL(kA_hist, dim3(NBLK), dim3(256), 0, stream, dstA, Hm);
    hipLaunchKernelGGL(k_scan_a, dim3(nb1), dim3(256), 0, stream, Hm, Sx, bsums, L);
    hipLaunchKernelGGL(k_scan_b, dim3(1), dim3(256), 0, stream, bsums, boffs, nb1);
    hipLaunchKernelGGL(k_scan_c, dim3((L + 255) / 256), dim3(256), 0, stream, Sx, boffs, L);
    hipLaunchKernelGGL(kA_scatter, dim3(NBLK), dim3(256), 0, stream, srcA, dstA, Sx, tmp);
    hipLaunchKernelGGL(kB_sort, dim3(NB), dim3(256), 0, stream, tmp, Sx, esrc, rs, deg);

    hipLaunchKernelGGL(k_prep, dim3(1), dim3(64), 0, stream, W2, as2, ad2, va_s, va_d);
    hipLaunchKernelGGL(k_gemm1, dim3(N_NODES / 8), dim3(256), 0, stream, x, W1, as1, ad1, h1A, h1B, s1, d1);
    hipLaunchKernelGGL(k_stats, dim3(N_NODES / 4), dim3(256), 0, stream, rs, deg, esrc, s1, d1, wbuf, idenS);
    hipLaunchKernelGGL(k_agg_pass, dim3(N_NODES / 4), dim3(256), 0, stream, rs, deg, esrc,
                       (const __half2*)h1A, wbuf, pA);
    hipLaunchKernelGGL(k_agg1b, dim3(N_NODES / 4), dim3(256), 0, stream, rs, deg, esrc,
                       (const __half2*)h1B, wbuf, pA, idenS, b1, va_s, va_d,
                       (__half2*)hrtA, (__half2*)hrtB, s2, d2);
    hipLaunchKernelGGL(k_stats, dim3(N_NODES / 4), dim3(256), 0, stream, rs, deg, esrc, s2, d2, wbuf, idenS);
    hipLaunchKernelGGL(k_agg_pass, dim3(N_NODES / 4), dim3(256), 0, stream, rs, deg, esrc,
                       (const __half2*)hrtA, wbuf, pA);
    hipLaunchKernelGGL(k_agg2b, dim3(N_NODES / 4), dim3(256), 0, stream, rs, deg, esrc,
                       (const __half2*)hrtB, wbuf, pA, idenS, W2, b2, out);
}

// Round 8
// 392.735 us; speedup vs baseline: 1.2074x; 1.2074x over previous
//
#include <hip/hip_runtime.h>
#include <hip/hip_bf16.h>
#include <hip/hip_fp16.h>
#include <math.h>

#define N_NODES 100000
#define N_EDGES 3200000
#define ET (N_EDGES + N_NODES)
#define F_IN 128
#define HID 32
#define NCLS 40
#define NEG 0.2f

// bucket sort geometry
#define NB 782
#define NBLK 782
#define CHUNK 4096
#define BCAP 6144

// ---------------- Pass A: bucket histogram ----------------
__global__ __launch_bounds__(256) void kA_hist(const int* __restrict__ dst,
                                               int* __restrict__ Hm) {
    __shared__ int hist[NB];
    int t = threadIdx.x, k = blockIdx.x;
    for (int i = t; i < NB; i += 256) hist[i] = 0;
    __syncthreads();
    int base = k * CHUNK;
#pragma unroll
    for (int j = 0; j < CHUNK / 256; j++) {
        int e = base + j * 256 + t;
        if (e < N_EDGES) atomicAdd(&hist[dst[e] >> 7], 1);
    }
    __syncthreads();
    for (int i = t; i < NB; i += 256) Hm[i * NBLK + k] = hist[i];
}

// ---------------- generic exclusive scan ----------------
__global__ void k_scan_a(const int* __restrict__ in, int* __restrict__ out,
                         int* __restrict__ bsums, int L) {
    __shared__ int sd[256];
    int t = threadIdx.x, b = blockIdx.x;
    int base = b * 1024 + t * 4;
    int v0 = 0, v1 = 0, v2 = 0, v3 = 0;
    if (base     < L) v0 = in[base];
    if (base + 1 < L) v1 = in[base + 1];
    if (base + 2 < L) v2 = in[base + 2];
    if (base + 3 < L) v3 = in[base + 3];
    int ts = v0 + v1 + v2 + v3;
    sd[t] = ts;
    __syncthreads();
    for (int off = 1; off < 256; off <<= 1) {
        int xx = (t >= off) ? sd[t - off] : 0;
        __syncthreads();
        sd[t] += xx;
        __syncthreads();
    }
    int ex = sd[t] - ts;
    if (t == 255) bsums[b] = sd[255];
    if (base     < L) out[base]     = ex;
    if (base + 1 < L) out[base + 1] = ex + v0;
    if (base + 2 < L) out[base + 2] = ex + v0 + v1;
    if (base + 3 < L) out[base + 3] = ex + v0 + v1 + v2;
}

__global__ void k_scan_b(const int* __restrict__ bsums, int* __restrict__ boffs, int nb) {
    __shared__ int sd[256];
    int t = threadIdx.x;
    int base = t * 4;
    int v0 = 0, v1 = 0, v2 = 0, v3 = 0;
    if (base     < nb) v0 = bsums[base];
    if (base + 1 < nb) v1 = bsums[base + 1];
    if (base + 2 < nb) v2 = bsums[base + 2];
    if (base + 3 < nb) v3 = bsums[base + 3];
    int ts = v0 + v1 + v2 + v3;
    sd[t] = ts;
    __syncthreads();
    for (int off = 1; off < 256; off <<= 1) {
        int xx = (t >= off) ? sd[t - off] : 0;
        __syncthreads();
        sd[t] += xx;
        __syncthreads();
    }
    int ex = sd[t] - ts;
    if (base     < nb) boffs[base]     = ex;
    if (base + 1 < nb) boffs[base + 1] = ex + v0;
    if (base + 2 < nb) boffs[base + 2] = ex + v0 + v1;
    if (base + 3 < nb) boffs[base + 3] = ex + v0 + v1 + v2;
}

__global__ void k_scan_c(int* __restrict__ out, const int* __restrict__ boffs, int L) {
    int i = blockIdx.x * 256 + threadIdx.x;
    if (i < L) out[i] += boffs[i >> 10];
}

// ---------------- Pass A: scatter into buckets ----------------
__global__ __launch_bounds__(256) void kA_scatter(
    const int* __restrict__ src, const int* __restrict__ dst,
    const int* __restrict__ Sx, unsigned int* __restrict__ tmp) {
    __shared__ int hist[NB];
    __shared__ int lofs[NB];
    __shared__ int cur[NB];
    __shared__ int tsum[256];
    __shared__ unsigned int stage[CHUNK];
    __shared__ int gpos[CHUNK];
    int t = threadIdx.x, k = blockIdx.x;
    for (int i = t; i < NB; i += 256) hist[i] = 0;
    __syncthreads();
    int base = k * CHUNK;
    int myd[16], mys[16];
#pragma unroll
    for (int j = 0; j < 16; j++) {
        int e = base + j * 256 + t;
        myd[j] = (e < N_EDGES) ? dst[e] : -1;
        mys[j] = (e < N_EDGES) ? src[e] : 0;
        if (myd[j] >= 0) atomicAdd(&hist[myd[j] >> 7], 1);
    }
    __syncthreads();
    int i0 = 4 * t;
    int h0 = (i0     < NB) ? hist[i0]     : 0;
    int h1 = (i0 + 1 < NB) ? hist[i0 + 1] : 0;
    int h2 = (i0 + 2 < NB) ? hist[i0 + 2] : 0;
    int h3 = (i0 + 3 < NB) ? hist[i0 + 3] : 0;
    int ts = h0 + h1 + h2 + h3;
    tsum[t] = ts;
    __syncthreads();
    for (int off = 1; off < 256; off <<= 1) {
        int xx = (t >= off) ? tsum[t - off] : 0;
        __syncthreads();
        tsum[t] += xx;
        __syncthreads();
    }
    int ex = tsum[t] - ts;
    if (i0     < NB) { lofs[i0]     = ex;                cur[i0]     = 0; }
    if (i0 + 1 < NB) { lofs[i0 + 1] = ex + h0;           cur[i0 + 1] = 0; }
    if (i0 + 2 < NB) { lofs[i0 + 2] = ex + h0 + h1;      cur[i0 + 2] = 0; }
    if (i0 + 3 < NB) { lofs[i0 + 3] = ex + h0 + h1 + h2; cur[i0 + 3] = 0; }
    __syncthreads();
#pragma unroll
    for (int j = 0; j < 16; j++) {
        if (myd[j] >= 0) {
            int bkt = myd[j] >> 7;
            int slot = lofs[bkt] + atomicAdd(&cur[bkt], 1);
            stage[slot] = ((unsigned int)(myd[j] & 127) << 17) | (unsigned int)mys[j];
            gpos[slot] = Sx[bkt * NBLK + k] + (slot - lofs[bkt]);
        }
    }
    __syncthreads();
    int nvalid = min(CHUNK, N_EDGES - base);
    for (int i = t; i < nvalid; i += 256) tmp[gpos[i]] = stage[i];
}

// ---------------- Pass B: per-bucket counting sort ----------------
__global__ __launch_bounds__(256) void kB_sort(
    const unsigned int* __restrict__ tmp, const int* __restrict__ Sx,
    int* __restrict__ esrc, int* __restrict__ rs, int* __restrict__ deg) {
    __shared__ unsigned int stage[BCAP];
    __shared__ int ordered[BCAP + 128];
    __shared__ int cnt[128], lofs[128], cur[128], sc[128];
    int t = threadIdx.x, b = blockIdx.x;
    int myBase = Sx[b * NBLK];
    int nextBase = (b == NB - 1) ? N_EDGES : Sx[(b + 1) * NBLK];
    int cntE = nextBase - myBase;
    int nNodes = min(128, N_NODES - b * 128);
    if (t < 128) { cnt[t] = 0; cur[t] = 0; }
    __syncthreads();
    for (int i = t; i < cntE; i += 256) {
        unsigned int p = tmp[myBase + i];
        stage[i] = p;
        atomicAdd(&cnt[p >> 17], 1);
    }
    __syncthreads();
    int val = 0;
    if (t < 128) { val = (t < nNodes) ? cnt[t] + 1 : 0; sc[t] = val; }
    __syncthreads();
    for (int off = 1; off < 128; off <<= 1) {
        int xx = 0;
        if (t < 128 && t >= off) xx = sc[t - off];
        __syncthreads();
        if (t < 128) sc[t] += xx;
        __syncthreads();
    }
    if (t < 128) lofs[t] = sc[t] - val;
    __syncthreads();
    if (t < nNodes) ordered[lofs[t]] = b * 128 + t;
    for (int i = t; i < cntE; i += 256) {
        unsigned int p = stage[i];
        int n = p >> 17;
        int slot = lofs[n] + 1 + atomicAdd(&cur[n], 1);
        ordered[slot] = (int)(p & 0x1FFFF);
    }
    __syncthreads();
    int gb = myBase + b * 128;
    int totOut = cntE + nNodes;
    for (int i = t; i < totOut; i += 256) esrc[gb + i] = ordered[i];
    if (t < nNodes) {
        rs[b * 128 + t] = gb + lofs[t];
        deg[b * 128 + t] = cnt[t] + 1;
    }
}

// ---------------- prep: va_s = W2 @ att_src2, va_d = W2 @ att_dst2 ----------------
__global__ void k_prep(const float* __restrict__ W2, const float* __restrict__ as2,
                       const float* __restrict__ ad2,
                       float* __restrict__ va_s, float* __restrict__ va_d) {
    int k = threadIdx.x;
    if (k < HID) {
        float ps = 0.f, pd = 0.f;
        for (int c = 0; c < NCLS; c++) {
            float w = W2[k * NCLS + c];
            ps = fmaf(w, as2[c], ps);
            pd = fmaf(w, ad2[c], pd);
        }
        va_s[k] = ps;
        va_d[k] = pd;
    }
}

// ---------------- GEMM1: h1 fp16 rows (64B) ; s1,d1 fp32 ----------------
__global__ __launch_bounds__(256) void k_gemm1(
    const float* __restrict__ x, const float* __restrict__ W1,
    const float* __restrict__ a_s, const float* __restrict__ a_d,
    __half* __restrict__ h1h, float* __restrict__ s1, float* __restrict__ d1) {
    __shared__ float Ws[F_IN * HID];
    __shared__ float xs[8 * F_IN];
    int t = threadIdx.x;
    const float4* W4 = (const float4*)W1;
    float4* Ws4 = (float4*)Ws;
#pragma unroll
    for (int i = 0; i < F_IN * HID / 4 / 256; i++)
        Ws4[t + i * 256] = W4[t + i * 256];
    ((float4*)xs)[t] = ((const float4*)(x + (size_t)blockIdx.x * 8 * F_IN))[t];
    __syncthreads();
    int c = t & 31, g = t >> 5;
    int v = blockIdx.x * 8 + g;
    const float4* xg4 = (const float4*)(xs + g * F_IN);
    float acc = 0.f;
#pragma unroll
    for (int k4 = 0; k4 < F_IN / 4; k4++) {
        float4 xv = xg4[k4];
        int k = k4 * 4;
        acc = fmaf(xv.x, Ws[(k + 0) * HID + c], acc);
        acc = fmaf(xv.y, Ws[(k + 1) * HID + c], acc);
        acc = fmaf(xv.z, Ws[(k + 2) * HID + c], acc);
        acc = fmaf(xv.w, Ws[(k + 3) * HID + c], acc);
    }
    h1h[(size_t)v * HID + c] = __float2half(acc);
    float p = acc * a_s[c];
    float q = acc * a_d[c];
    for (int mm = 16; mm >= 1; mm >>= 1) {
        p += __shfl_xor(p, mm, 32);
        q += __shfl_xor(q, mm, 32);
    }
    if (c == 0) { s1[v] = p; d1[v] = q; }
}

// ---------------- fused layer-1 edge sweep: softmax + gather + hr + s2/d2 ----------
// wave/node; 16 edges x 4 quad-lanes; each lane gathers 16B (quarter row)
__global__ __launch_bounds__(256) void k_fused1(
    const int* __restrict__ rs, const int* __restrict__ deg, const int* __restrict__ esrc,
    const uint4* __restrict__ h1r, const float* __restrict__ s1, const float* __restrict__ d1,
    const float* __restrict__ b1, const float* __restrict__ va_s, const float* __restrict__ va_d,
    uint4* __restrict__ hrr, float* __restrict__ s2, float* __restrict__ d2) {
    int lane = threadIdx.x & 63;
    int v = blockIdx.x * 4 + (threadIdx.x >> 6);
    int q = lane & 3;
    int e = lane >> 2;   // 0..15
    int start = rs[v];
    int cnt = deg[v];
    float dval = d1[v];
    float a0 = 0.f, a1 = 0.f, a2 = 0.f, a3 = 0.f, a4 = 0.f, a5 = 0.f, a6 = 0.f, a7 = 0.f;
    float den = 0.f;
#pragma unroll 2
    for (int t = 0; t < cnt; t += 16) {
        int idx = t + e;
        int sa = 0;
        float w = 0.f;
        if (idx < cnt) {
            sa = esrc[start + idx];
            float ev = s1[sa] + dval;
            ev = (ev >= 0.f) ? ev : NEG * ev;
            w = __expf(ev);     // logits O(+-7): safe without max shift
        }
        uint4 hv = h1r[(size_t)sa * 4 + q];
        float2 f0 = __half22float2(*(const __half2*)&hv.x);
        float2 f1 = __half22float2(*(const __half2*)&hv.y);
        float2 f2 = __half22float2(*(const __half2*)&hv.z);
        float2 f3 = __half22float2(*(const __half2*)&hv.w);
        a0 = fmaf(w, f0.x, a0); a1 = fmaf(w, f0.y, a1);
        a2 = fmaf(w, f1.x, a2); a3 = fmaf(w, f1.y, a3);
        a4 = fmaf(w, f2.x, a4); a5 = fmaf(w, f2.y, a5);
        a6 = fmaf(w, f3.x, a6); a7 = fmaf(w, f3.y, a7);
        den += w;
    }
    // reduce across the 16 edge-lanes (bits 2..5)
#pragma unroll
    for (int off = 4; off <= 32; off <<= 1) {
        a0 += __shfl_xor(a0, off); a1 += __shfl_xor(a1, off);
        a2 += __shfl_xor(a2, off); a3 += __shfl_xor(a3, off);
        a4 += __shfl_xor(a4, off); a5 += __shfl_xor(a5, off);
        a6 += __shfl_xor(a6, off); a7 += __shfl_xor(a7, off);
        den += __shfl_xor(den, off);
    }
    if (e == 0) {
        float iden = 1.f / den;
        const float4* b4 = (const float4*)(b1 + q * 8);
        float4 bA = b4[0], bB = b4[1];
        float o0 = fmaxf(a0 * iden + bA.x, 0.f);
        float o1 = fmaxf(a1 * iden + bA.y, 0.f);
        float o2 = fmaxf(a2 * iden + bA.z, 0.f);
        float o3 = fmaxf(a3 * iden + bA.w, 0.f);
        float o4 = fmaxf(a4 * iden + bB.x, 0.f);
        float o5 = fmaxf(a5 * iden + bB.y, 0.f);
        float o6 = fmaxf(a6 * iden + bB.z, 0.f);
        float o7 = fmaxf(a7 * iden + bB.w, 0.f);
        __half2 p0 = __floats2half2_rn(o0, o1);
        __half2 p1 = __floats2half2_rn(o2, o3);
        __half2 p2 = __floats2half2_rn(o4, o5);
        __half2 p3 = __floats2half2_rn(o6, o7);
        uint4 ov;
        ov.x = *(const unsigned int*)&p0;
        ov.y = *(const unsigned int*)&p1;
        ov.z = *(const unsigned int*)&p2;
        ov.w = *(const unsigned int*)&p3;
        hrr[(size_t)v * 4 + q] = ov;
        const float4* vs4 = (const float4*)(va_s + q * 8);
        const float4* vd4 = (const float4*)(va_d + q * 8);
        float4 sA = vs4[0], sB = vs4[1], dA = vd4[0], dB = vd4[1];
        float ps = o0 * sA.x + o1 * sA.y + o2 * sA.z + o3 * sA.w
                 + o4 * sB.x + o5 * sB.y + o6 * sB.z + o7 * sB.w;
        float pd = o0 * dA.x + o1 * dA.y + o2 * dA.z + o3 * dA.w
                 + o4 * dB.x + o5 * dB.y + o6 * dB.z + o7 * dB.w;
        ps += __shfl_xor(ps, 1); pd += __shfl_xor(pd, 1);
        ps += __shfl_xor(ps, 2); pd += __shfl_xor(pd, 2);
        if (q == 0) { s2[v] = ps; d2[v] = pd; }
    }
}

// ---------------- fused layer-2 edge sweep: softmax + gather + @W2 + log_softmax ----
__global__ __launch_bounds__(256) void k_fused2(
    const int* __restrict__ rs, const int* __restrict__ deg, const int* __restrict__ esrc,
    const uint4* __restrict__ hrr, const float* __restrict__ s2, const float* __restrict__ d2,
    const float* __restrict__ W2, const float* __restrict__ b2, float* __restrict__ out) {
    __shared__ float W2s[HID * NCLS];   // 5 KB
    __shared__ float hragg[4][HID];
    int tid = threadIdx.x;
    for (int i = tid; i < HID * NCLS; i += 256) W2s[i] = W2[i];
    __syncthreads();
    int lane = tid & 63;
    int wid = tid >> 6;
    int v = blockIdx.x * 4 + wid;
    int q = lane & 3;
    int e = lane >> 2;
    int start = rs[v];
    int cnt = deg[v];
    float dval = d2[v];
    float a0 = 0.f, a1 = 0.f, a2 = 0.f, a3 = 0.f, a4 = 0.f, a5 = 0.f, a6 = 0.f, a7 = 0.f;
    float den = 0.f;
#pragma unroll 2
    for (int t = 0; t < cnt; t += 16) {
        int idx = t + e;
        int sa = 0;
        float w = 0.f;
        if (idx < cnt) {
            sa = esrc[start + idx];
            float ev = s2[sa] + dval;
            ev = (ev >= 0.f) ? ev : NEG * ev;
            w = __expf(ev);
        }
        uint4 hv = hrr[(size_t)sa * 4 + q];
        float2 f0 = __half22float2(*(const __half2*)&hv.x);
        float2 f1 = __half22float2(*(const __half2*)&hv.y);
        float2 f2 = __half22float2(*(const __half2*)&hv.z);
        float2 f3 = __half22float2(*(const __half2*)&hv.w);
        a0 = fmaf(w, f0.x, a0); a1 = fmaf(w, f0.y, a1);
        a2 = fmaf(w, f1.x, a2); a3 = fmaf(w, f1.y, a3);
        a4 = fmaf(w, f2.x, a4); a5 = fmaf(w, f2.y, a5);
        a6 = fmaf(w, f3.x, a6); a7 = fmaf(w, f3.y, a7);
        den += w;
    }
#pragma unroll
    for (int off = 4; off <= 32; off <<= 1) {
        a0 += __shfl_xor(a0, off); a1 += __shfl_xor(a1, off);
        a2 += __shfl_xor(a2, off); a3 += __shfl_xor(a3, off);
        a4 += __shfl_xor(a4, off); a5 += __shfl_xor(a5, off);
        a6 += __shfl_xor(a6, off); a7 += __shfl_xor(a7, off);
        den += __shfl_xor(den, off);
    }
    if (e == 0) {
        float iden = 1.f / den;
        int cbase = q * 8;
        hragg[wid][cbase + 0] = a0 * iden;
        hragg[wid][cbase + 1] = a1 * iden;
        hragg[wid][cbase + 2] = a2 * iden;
        hragg[wid][cbase + 3] = a3 * iden;
        hragg[wid][cbase + 4] = a4 * iden;
        hragg[wid][cbase + 5] = a5 * iden;
        hragg[wid][cbase + 6] = a6 * iden;
        hragg[wid][cbase + 7] = a7 * iden;
    }
    __syncthreads();
    // epilogue: z = hragg @ W2 + b2 ; relu ; log_softmax over 40 classes
    float z = 0.f;
    if (lane < NCLS) {
#pragma unroll
        for (int k = 0; k < HID; k++)
            z = fmaf(hragg[wid][k], W2s[k * NCLS + lane], z);
        z = fmaxf(z + b2[lane], 0.f);
    }
    float mz = (lane < NCLS) ? z : -INFINITY;
    for (int mm = 32; mm >= 1; mm >>= 1) mz = fmaxf(mz, __shfl_xor(mz, mm));
    float ex = (lane < NCLS) ? __expf(z - mz) : 0.f;
    float se = ex;
    for (int mm = 32; mm >= 1; mm >>= 1) se += __shfl_xor(se, mm);
    if (lane < NCLS) out[(size_t)v * NCLS + lane] = z - mz - logf(se);
}

// ---------------- launch ----------------

extern "C" void kernel_launch(void* const* d_in, const int* in_sizes, int n_in,
                              void* d_out, int out_size, void* d_ws, size_t ws_size,
                              hipStream_t stream) {
    (void)in_sizes; (void)n_in; (void)out_size; (void)ws_size;
    const float* x   = (const float*)d_in[0];
    const int*   ei  = (const int*)d_in[1];
    const float* W1  = (const float*)d_in[2];
    const float* as1 = (const float*)d_in[3];
    const float* ad1 = (const float*)d_in[4];
    const float* b1  = (const float*)d_in[5];
    const float* W2  = (const float*)d_in[6];
    const float* as2 = (const float*)d_in[7];
    const float* ad2 = (const float*)d_in[8];
    const float* b2  = (const float*)d_in[9];
    float* out = (float*)d_out;
    const int* srcA = ei;
    const int* dstA = ei + N_EDGES;

    char* w = (char*)d_ws;
    size_t off = 0;
    auto alloc = [&](size_t bytes) {
        char* p = w + off;
        off = (off + bytes + 255) & ~(size_t)255;
        return p;
    };
    int* esrc     = (int*)alloc((size_t)ET * 4);
    int* rs       = (int*)alloc((size_t)N_NODES * 4);
    int* deg      = (int*)alloc((size_t)N_NODES * 4);
    char* region1 = alloc((size_t)N_NODES * HID * 4);   // Hm/Sx during build, then h1h (6.4MB)
    float* s1     = (float*)alloc((size_t)N_NODES * 4);
    float* d1     = (float*)alloc((size_t)N_NODES * 4);
    char* region2 = alloc((size_t)N_EDGES * 4 + 1024);  // tmp during build, then hrt (6.4MB)
    float* s2     = (float*)alloc((size_t)N_NODES * 4);
    float* d2     = (float*)alloc((size_t)N_NODES * 4);
    float* va_s   = (float*)alloc(HID * 4);
    float* va_d   = (float*)alloc(HID * 4);
    int* bsums    = (int*)alloc(1024 * 4);
    int* boffs    = (int*)alloc(1024 * 4);

    const int L = NB * NBLK;
    int* Hm = (int*)region1;
    int* Sx = Hm + ((L + 63) & ~63);
    __half* h1h = (__half*)region1;              // fp16 rows after build
    unsigned int* tmp = (unsigned int*)region2;
    __half* hrt = (__half*)region2;              // hr fp16 rows after build

    int nb1 = (L + 1023) / 1024;
    hipLaunchKernelGGL(kA_hist, dim3(NBLK), dim3(256), 0, stream, dstA, Hm);
    hipLaunchKernelGGL(k_scan_a, dim3(nb1), dim3(256), 0, stream, Hm, Sx, bsums, L);
    hipLaunchKernelGGL(k_scan_b, dim3(1), dim3(256), 0, stream, bsums, boffs, nb1);
    hipLaunchKernelGGL(k_scan_c, dim3((L + 255) / 256), dim3(256), 0, stream, Sx, boffs, L);
    hipLaunchKernelGGL(kA_scatter, dim3(NBLK), dim3(256), 0, stream, srcA, dstA, Sx, tmp);
    hipLaunchKernelGGL(kB_sort, dim3(NB), dim3(256), 0, stream, tmp, Sx, esrc, rs, deg);

    hipLaunchKernelGGL(k_prep, dim3(1), dim3(64), 0, stream, W2, as2, ad2, va_s, va_d);
    hipLaunchKernelGGL(k_gemm1, dim3(N_NODES / 8), dim3(256), 0, stream, x, W1, as1, ad1, h1h, s1, d1);
    hipLaunchKernelGGL(k_fused1, dim3(N_NODES / 4), dim3(256), 0, stream, rs, deg, esrc,
                       (const uint4*)h1h, s1, d1, b1, va_s, va_d,
                       (uint4*)hrt, s2, d2);
    hipLaunchKernelGGL(k_fused2, dim3(N_NODES / 4), dim3(256), 0, stream, rs, deg, esrc,
                       (const uint4*)hrt, s2, d2, W2, b2, out);
}

// Round 9
// 349.115 us; speedup vs baseline: 1.3582x; 1.1249x over previous
//
#include <hip/hip_runtime.h>
#include <hip/hip_bf16.h>
#include <hip/hip_fp16.h>
#include <math.h>

#define N_NODES 100000
#define N_EDGES 3200000
#define ET (N_EDGES + N_NODES)
#define F_IN 128
#define HID 32
#define NCLS 40
#define NEG 0.2f

// bucket sort geometry
#define NB 782
#define NBLK 782
#define CHUNK 4096
#define BCAP 6144

// ---------------- Pass A: bucket histogram ----------------
__global__ __launch_bounds__(256) void kA_hist(const int* __restrict__ dst,
                                               int* __restrict__ Hm) {
    __shared__ int hist[NB];
    int t = threadIdx.x, k = blockIdx.x;
    for (int i = t; i < NB; i += 256) hist[i] = 0;
    __syncthreads();
    int base = k * CHUNK;
#pragma unroll
    for (int j = 0; j < CHUNK / 256; j++) {
        int e = base + j * 256 + t;
        if (e < N_EDGES) atomicAdd(&hist[dst[e] >> 7], 1);
    }
    __syncthreads();
    for (int i = t; i < NB; i += 256) Hm[i * NBLK + k] = hist[i];
}

// ---------------- generic exclusive scan ----------------
__global__ void k_scan_a(const int* __restrict__ in, int* __restrict__ out,
                         int* __restrict__ bsums, int L) {
    __shared__ int sd[256];
    int t = threadIdx.x, b = blockIdx.x;
    int base = b * 1024 + t * 4;
    int v0 = 0, v1 = 0, v2 = 0, v3 = 0;
    if (base     < L) v0 = in[base];
    if (base + 1 < L) v1 = in[base + 1];
    if (base + 2 < L) v2 = in[base + 2];
    if (base + 3 < L) v3 = in[base + 3];
    int ts = v0 + v1 + v2 + v3;
    sd[t] = ts;
    __syncthreads();
    for (int off = 1; off < 256; off <<= 1) {
        int xx = (t >= off) ? sd[t - off] : 0;
        __syncthreads();
        sd[t] += xx;
        __syncthreads();
    }
    int ex = sd[t] - ts;
    if (t == 255) bsums[b] = sd[255];
    if (base     < L) out[base]     = ex;
    if (base + 1 < L) out[base + 1] = ex + v0;
    if (base + 2 < L) out[base + 2] = ex + v0 + v1;
    if (base + 3 < L) out[base + 3] = ex + v0 + v1 + v2;
}

__global__ void k_scan_b(const int* __restrict__ bsums, int* __restrict__ boffs, int nb) {
    __shared__ int sd[256];
    int t = threadIdx.x;
    int base = t * 4;
    int v0 = 0, v1 = 0, v2 = 0, v3 = 0;
    if (base     < nb) v0 = bsums[base];
    if (base + 1 < nb) v1 = bsums[base + 1];
    if (base + 2 < nb) v2 = bsums[base + 2];
    if (base + 3 < nb) v3 = bsums[base + 3];
    int ts = v0 + v1 + v2 + v3;
    sd[t] = ts;
    __syncthreads();
    for (int off = 1; off < 256; off <<= 1) {
        int xx = (t >= off) ? sd[t - off] : 0;
        __syncthreads();
        sd[t] += xx;
        __syncthreads();
    }
    int ex = sd[t] - ts;
    if (base     < nb) boffs[base]     = ex;
    if (base + 1 < nb) boffs[base + 1] = ex + v0;
    if (base + 2 < nb) boffs[base + 2] = ex + v0 + v1;
    if (base + 3 < nb) boffs[base + 3] = ex + v0 + v1 + v2;
}

__global__ void k_scan_c(int* __restrict__ out, const int* __restrict__ boffs, int L) {
    int i = blockIdx.x * 256 + threadIdx.x;
    if (i < L) out[i] += boffs[i >> 10];
}

// ---------------- Pass A: scatter into buckets ----------------
__global__ __launch_bounds__(256) void kA_scatter(
    const int* __restrict__ src, const int* __restrict__ dst,
    const int* __restrict__ Sx, unsigned int* __restrict__ tmp) {
    __shared__ int hist[NB];
    __shared__ int lofs[NB];
    __shared__ int cur[NB];
    __shared__ int tsum[256];
    __shared__ unsigned int stage[CHUNK];
    __shared__ int gpos[CHUNK];
    int t = threadIdx.x, k = blockIdx.x;
    for (int i = t; i < NB; i += 256) hist[i] = 0;
    __syncthreads();
    int base = k * CHUNK;
    int myd[16], mys[16];
#pragma unroll
    for (int j = 0; j < 16; j++) {
        int e = base + j * 256 + t;
        myd[j] = (e < N_EDGES) ? dst[e] : -1;
        mys[j] = (e < N_EDGES) ? src[e] : 0;
        if (myd[j] >= 0) atomicAdd(&hist[myd[j] >> 7], 1);
    }
    __syncthreads();
    int i0 = 4 * t;
    int h0 = (i0     < NB) ? hist[i0]     : 0;
    int h1 = (i0 + 1 < NB) ? hist[i0 + 1] : 0;
    int h2 = (i0 + 2 < NB) ? hist[i0 + 2] : 0;
    int h3 = (i0 + 3 < NB) ? hist[i0 + 3] : 0;
    int ts = h0 + h1 + h2 + h3;
    tsum[t] = ts;
    __syncthreads();
    for (int off = 1; off < 256; off <<= 1) {
        int xx = (t >= off) ? tsum[t - off] : 0;
        __syncthreads();
        tsum[t] += xx;
        __syncthreads();
    }
    int ex = tsum[t] - ts;
    if (i0     < NB) { lofs[i0]     = ex;                cur[i0]     = 0; }
    if (i0 + 1 < NB) { lofs[i0 + 1] = ex + h0;           cur[i0 + 1] = 0; }
    if (i0 + 2 < NB) { lofs[i0 + 2] = ex + h0 + h1;      cur[i0 + 2] = 0; }
    if (i0 + 3 < NB) { lofs[i0 + 3] = ex + h0 + h1 + h2; cur[i0 + 3] = 0; }
    __syncthreads();
#pragma unroll
    for (int j = 0; j < 16; j++) {
        if (myd[j] >= 0) {
            int bkt = myd[j] >> 7;
            int slot = lofs[bkt] + atomicAdd(&cur[bkt], 1);
            stage[slot] = ((unsigned int)(myd[j] & 127) << 17) | (unsigned int)mys[j];
            gpos[slot] = Sx[bkt * NBLK + k] + (slot - lofs[bkt]);
        }
    }
    __syncthreads();
    int nvalid = min(CHUNK, N_EDGES - base);
    for (int i = t; i < nvalid; i += 256) tmp[gpos[i]] = stage[i];
}

// ---------------- Pass B: per-bucket counting sort ----------------
__global__ __launch_bounds__(256) void kB_sort(
    const unsigned int* __restrict__ tmp, const int* __restrict__ Sx,
    int* __restrict__ esrc, int* __restrict__ rs, int* __restrict__ deg) {
    __shared__ unsigned int stage[BCAP];
    __shared__ int ordered[BCAP + 128];
    __shared__ int cnt[128], lofs[128], cur[128], sc[128];
    int t = threadIdx.x, b = blockIdx.x;
    int myBase = Sx[b * NBLK];
    int nextBase = (b == NB - 1) ? N_EDGES : Sx[(b + 1) * NBLK];
    int cntE = nextBase - myBase;
    int nNodes = min(128, N_NODES - b * 128);
    if (t < 128) { cnt[t] = 0; cur[t] = 0; }
    __syncthreads();
    for (int i = t; i < cntE; i += 256) {
        unsigned int p = tmp[myBase + i];
        stage[i] = p;
        atomicAdd(&cnt[p >> 17], 1);
    }
    __syncthreads();
    int val = 0;
    if (t < 128) { val = (t < nNodes) ? cnt[t] + 1 : 0; sc[t] = val; }
    __syncthreads();
    for (int off = 1; off < 128; off <<= 1) {
        int xx = 0;
        if (t < 128 && t >= off) xx = sc[t - off];
        __syncthreads();
        if (t < 128) sc[t] += xx;
        __syncthreads();
    }
    if (t < 128) lofs[t] = sc[t] - val;
    __syncthreads();
    if (t < nNodes) ordered[lofs[t]] = b * 128 + t;
    for (int i = t; i < cntE; i += 256) {
        unsigned int p = stage[i];
        int n = p >> 17;
        int slot = lofs[n] + 1 + atomicAdd(&cur[n], 1);
        ordered[slot] = (int)(p & 0x1FFFF);
    }
    __syncthreads();
    int gb = myBase + b * 128;
    int totOut = cntE + nNodes;
    for (int i = t; i < totOut; i += 256) esrc[gb + i] = ordered[i];
    if (t < nNodes) {
        rs[b * 128 + t] = gb + lofs[t];
        deg[b * 128 + t] = cnt[t] + 1;
    }
}

// ---------------- prep: va_s = W2 @ att_src2, va_d = W2 @ att_dst2 ----------------
__global__ void k_prep(const float* __restrict__ W2, const float* __restrict__ as2,
                       const float* __restrict__ ad2,
                       float* __restrict__ va_s, float* __restrict__ va_d) {
    int k = threadIdx.x;
    if (k < HID) {
        float ps = 0.f, pd = 0.f;
        for (int c = 0; c < NCLS; c++) {
            float w = W2[k * NCLS + c];
            ps = fmaf(w, as2[c], ps);
            pd = fmaf(w, ad2[c], pd);
        }
        va_s[k] = ps;
        va_d[k] = pd;
    }
}

// ---------------- GEMM1: h1 fp16 rows (64B) ; s1,d1 fp32 ----------------
__global__ __launch_bounds__(256) void k_gemm1(
    const float* __restrict__ x, const float* __restrict__ W1,
    const float* __restrict__ a_s, const float* __restrict__ a_d,
    __half* __restrict__ h1h, float* __restrict__ s1, float* __restrict__ d1) {
    __shared__ float Ws[F_IN * HID];
    __shared__ float xs[8 * F_IN];
    int t = threadIdx.x;
    const float4* W4 = (const float4*)W1;
    float4* Ws4 = (float4*)Ws;
#pragma unroll
    for (int i = 0; i < F_IN * HID / 4 / 256; i++)
        Ws4[t + i * 256] = W4[t + i * 256];
    ((float4*)xs)[t] = ((const float4*)(x + (size_t)blockIdx.x * 8 * F_IN))[t];
    __syncthreads();
    int c = t & 31, g = t >> 5;
    int v = blockIdx.x * 8 + g;
    const float4* xg4 = (const float4*)(xs + g * F_IN);
    float acc = 0.f;
#pragma unroll
    for (int k4 = 0; k4 < F_IN / 4; k4++) {
        float4 xv = xg4[k4];
        int k = k4 * 4;
        acc = fmaf(xv.x, Ws[(k + 0) * HID + c], acc);
        acc = fmaf(xv.y, Ws[(k + 1) * HID + c], acc);
        acc = fmaf(xv.z, Ws[(k + 2) * HID + c], acc);
        acc = fmaf(xv.w, Ws[(k + 3) * HID + c], acc);
    }
    h1h[(size_t)v * HID + c] = __float2half(acc);
    float p = acc * a_s[c];
    float q = acc * a_d[c];
    for (int mm = 16; mm >= 1; mm >>= 1) {
        p += __shfl_xor(p, mm, 32);
        q += __shfl_xor(q, mm, 32);
    }
    if (c == 0) { s1[v] = p; d1[v] = q; }
}

// ---------------- fused layer-1 sweep: 4 nodes/wave (16 lanes: 4 edges x 4 quads) ----
__global__ __launch_bounds__(256) void k_fused1(
    const int* __restrict__ rs, const int* __restrict__ deg, const int* __restrict__ esrc,
    const uint4* __restrict__ h1r, const float* __restrict__ s1, const float* __restrict__ d1,
    const float* __restrict__ b1, const float* __restrict__ va_s, const float* __restrict__ va_d,
    uint4* __restrict__ hrr, float* __restrict__ s2, float* __restrict__ d2) {
    int tid = threadIdx.x;
    int sub = tid & 15;      // lane within quarter-wave
    int q = sub & 3;         // 16B chunk of the row
    int e = sub >> 2;        // edge slot 0..3
    int v = blockIdx.x * 16 + (tid >> 4);
    int start = rs[v];
    int cnt = deg[v];
    float dval = d1[v];
    float a0 = 0.f, a1 = 0.f, a2 = 0.f, a3 = 0.f, a4 = 0.f, a5 = 0.f, a6 = 0.f, a7 = 0.f;
    float den = 0.f;
#pragma unroll 2
    for (int t = 0; t < cnt; t += 4) {
        int idx = t + e;
        int sa = 0;
        float w = 0.f;
        if (idx < cnt) {
            sa = esrc[start + idx];
            float ev = s1[sa] + dval;
            ev = (ev >= 0.f) ? ev : NEG * ev;
            w = __expf(ev);     // logits O(+-7): safe without max shift
        }
        uint4 hv = h1r[(size_t)sa * 4 + q];
        float2 f0 = __half22float2(*(const __half2*)&hv.x);
        float2 f1 = __half22float2(*(const __half2*)&hv.y);
        float2 f2 = __half22float2(*(const __half2*)&hv.z);
        float2 f3 = __half22float2(*(const __half2*)&hv.w);
        a0 = fmaf(w, f0.x, a0); a1 = fmaf(w, f0.y, a1);
        a2 = fmaf(w, f1.x, a2); a3 = fmaf(w, f1.y, a3);
        a4 = fmaf(w, f2.x, a4); a5 = fmaf(w, f2.y, a5);
        a6 = fmaf(w, f3.x, a6); a7 = fmaf(w, f3.y, a7);
        den += w;
    }
    // reduce across the 4 edge lanes (bits 2,3) — stays within the quarter
#pragma unroll
    for (int off = 4; off <= 8; off <<= 1) {
        a0 += __shfl_xor(a0, off); a1 += __shfl_xor(a1, off);
        a2 += __shfl_xor(a2, off); a3 += __shfl_xor(a3, off);
        a4 += __shfl_xor(a4, off); a5 += __shfl_xor(a5, off);
        a6 += __shfl_xor(a6, off); a7 += __shfl_xor(a7, off);
        den += __shfl_xor(den, off);
    }
    if (e == 0) {
        float iden = 1.f / den;
        const float4* b4 = (const float4*)(b1 + q * 8);
        float4 bA = b4[0], bB = b4[1];
        float o0 = fmaxf(a0 * iden + bA.x, 0.f);
        float o1 = fmaxf(a1 * iden + bA.y, 0.f);
        float o2 = fmaxf(a2 * iden + bA.z, 0.f);
        float o3 = fmaxf(a3 * iden + bA.w, 0.f);
        float o4 = fmaxf(a4 * iden + bB.x, 0.f);
        float o5 = fmaxf(a5 * iden + bB.y, 0.f);
        float o6 = fmaxf(a6 * iden + bB.z, 0.f);
        float o7 = fmaxf(a7 * iden + bB.w, 0.f);
        __half2 p0 = __floats2half2_rn(o0, o1);
        __half2 p1 = __floats2half2_rn(o2, o3);
        __half2 p2 = __floats2half2_rn(o4, o5);
        __half2 p3 = __floats2half2_rn(o6, o7);
        uint4 ov;
        ov.x = *(const unsigned int*)&p0;
        ov.y = *(const unsigned int*)&p1;
        ov.z = *(const unsigned int*)&p2;
        ov.w = *(const unsigned int*)&p3;
        hrr[(size_t)v * 4 + q] = ov;
        const float4* vs4 = (const float4*)(va_s + q * 8);
        const float4* vd4 = (const float4*)(va_d + q * 8);
        float4 sA = vs4[0], sB = vs4[1], dA = vd4[0], dB = vd4[1];
        float ps = o0 * sA.x + o1 * sA.y + o2 * sA.z + o3 * sA.w
                 + o4 * sB.x + o5 * sB.y + o6 * sB.z + o7 * sB.w;
        float pd = o0 * dA.x + o1 * dA.y + o2 * dA.z + o3 * dA.w
                 + o4 * dB.x + o5 * dB.y + o6 * dB.z + o7 * dB.w;
        // combine the 4 q-lanes (lanes sub=0..3, consecutive)
        ps += __shfl_xor(ps, 1); pd += __shfl_xor(pd, 1);
        ps += __shfl_xor(ps, 2); pd += __shfl_xor(pd, 2);
        if (q == 0) { s2[v] = ps; d2[v] = pd; }
    }
}

// ---------------- fused layer-2 sweep: 4 nodes/wave + @W2 + log_softmax ----------
__global__ __launch_bounds__(256) void k_fused2(
    const int* __restrict__ rs, const int* __restrict__ deg, const int* __restrict__ esrc,
    const uint4* __restrict__ hrr, const float* __restrict__ s2, const float* __restrict__ d2,
    const float* __restrict__ W2, const float* __restrict__ b2, float* __restrict__ out) {
    __shared__ float W2s[HID * NCLS];     // 5 KB
    __shared__ float hragg[16][HID];      // 2 KB
    __shared__ float zbuf[16][NCLS];      // 2.5 KB
    __shared__ float gm[16], gl[16];
    int tid = threadIdx.x;
    for (int i = tid; i < HID * NCLS; i += 256) W2s[i] = W2[i];
    int sub = tid & 15;
    int q = sub & 3;
    int e = sub >> 2;
    int node = tid >> 4;               // 0..15 within block
    int v = blockIdx.x * 16 + node;
    int start = rs[v];
    int cnt = deg[v];
    float dval = d2[v];
    float a0 = 0.f, a1 = 0.f, a2 = 0.f, a3 = 0.f, a4 = 0.f, a5 = 0.f, a6 = 0.f, a7 = 0.f;
    float den = 0.f;
#pragma unroll 2
    for (int t = 0; t < cnt; t += 4) {
        int idx = t + e;
        int sa = 0;
        float w = 0.f;
        if (idx < cnt) {
            sa = esrc[start + idx];
            float ev = s2[sa] + dval;
            ev = (ev >= 0.f) ? ev : NEG * ev;
            w = __expf(ev);
        }
        uint4 hv = hrr[(size_t)sa * 4 + q];
        float2 f0 = __half22float2(*(const __half2*)&hv.x);
        float2 f1 = __half22float2(*(const __half2*)&hv.y);
        float2 f2 = __half22float2(*(const __half2*)&hv.z);
        float2 f3 = __half22float2(*(const __half2*)&hv.w);
        a0 = fmaf(w, f0.x, a0); a1 = fmaf(w, f0.y, a1);
        a2 = fmaf(w, f1.x, a2); a3 = fmaf(w, f1.y, a3);
        a4 = fmaf(w, f2.x, a4); a5 = fmaf(w, f2.y, a5);
        a6 = fmaf(w, f3.x, a6); a7 = fmaf(w, f3.y, a7);
        den += w;
    }
#pragma unroll
    for (int off = 4; off <= 8; off <<= 1) {
        a0 += __shfl_xor(a0, off); a1 += __shfl_xor(a1, off);
        a2 += __shfl_xor(a2, off); a3 += __shfl_xor(a3, off);
        a4 += __shfl_xor(a4, off); a5 += __shfl_xor(a5, off);
        a6 += __shfl_xor(a6, off); a7 += __shfl_xor(a7, off);
        den += __shfl_xor(den, off);
    }
    if (e == 0) {
        float iden = 1.f / den;
        int cb = q * 8;
        hragg[node][cb + 0] = a0 * iden;
        hragg[node][cb + 1] = a1 * iden;
        hragg[node][cb + 2] = a2 * iden;
        hragg[node][cb + 3] = a3 * iden;
        hragg[node][cb + 4] = a4 * iden;
        hragg[node][cb + 5] = a5 * iden;
        hragg[node][cb + 6] = a6 * iden;
        hragg[node][cb + 7] = a7 * iden;
    }
    __syncthreads();
    // z = hragg @ W2 + b2, relu — 640 outputs over 256 threads
    for (int oi = tid; oi < 16 * NCLS; oi += 256) {
        int n = oi / NCLS, c = oi % NCLS;
        float z = 0.f;
#pragma unroll
        for (int k = 0; k < HID; k++)
            z = fmaf(hragg[n][k], W2s[k * NCLS + c], z);
        zbuf[n][c] = fmaxf(z + b2[c], 0.f);
    }
    __syncthreads();
    if (tid < 16) {
        float mx = -INFINITY;
        for (int c = 0; c < NCLS; c++) mx = fmaxf(mx, zbuf[tid][c]);
        float se = 0.f;
        for (int c = 0; c < NCLS; c++) se += __expf(zbuf[tid][c] - mx);
        gm[tid] = mx;
        gl[tid] = logf(se);
    }
    __syncthreads();
    for (int oi = tid; oi < 16 * NCLS; oi += 256) {
        int n = oi / NCLS, c = oi % NCLS;
        out[(size_t)(blockIdx.x * 16 + n) * NCLS + c] = zbuf[n][c] - gm[n] - gl[n];
    }
}

// ---------------- launch ----------------

extern "C" void kernel_launch(void* const* d_in, const int* in_sizes, int n_in,
                              void* d_out, int out_size, void* d_ws, size_t ws_size,
                              hipStream_t stream) {
    (void)in_sizes; (void)n_in; (void)out_size; (void)ws_size;
    const float* x   = (const float*)d_in[0];
    const int*   ei  = (const int*)d_in[1];
    const float* W1  = (const float*)d_in[2];
    const float* as1 = (const float*)d_in[3];
    const float* ad1 = (const float*)d_in[4];
    const float* b1  = (const float*)d_in[5];
    const float* W2  = (const float*)d_in[6];
    const float* as2 = (const float*)d_in[7];
    const float* ad2 = (const float*)d_in[8];
    const float* b2  = (const float*)d_in[9];
    float* out = (float*)d_out;
    const int* srcA = ei;
    const int* dstA = ei + N_EDGES;

    char* w = (char*)d_ws;
    size_t off = 0;
    auto alloc = [&](size_t bytes) {
        char* p = w + off;
        off = (off + bytes + 255) & ~(size_t)255;
        return p;
    };
    int* esrc     = (int*)alloc((size_t)ET * 4);
    int* rs       = (int*)alloc((size_t)N_NODES * 4);
    int* deg      = (int*)alloc((size_t)N_NODES * 4);
    char* region1 = alloc((size_t)N_NODES * HID * 4);   // Hm/Sx during build, then h1h (6.4MB)
    float* s1     = (float*)alloc((size_t)N_NODES * 4);
    float* d1     = (float*)alloc((size_t)N_NODES * 4);
    char* region2 = alloc((size_t)N_EDGES * 4 + 1024);  // tmp during build, then hrt (6.4MB)
    float* s2     = (float*)alloc((size_t)N_NODES * 4);
    float* d2     = (float*)alloc((size_t)N_NODES * 4);
    float* va_s   = (float*)alloc(HID * 4);
    float* va_d   = (float*)alloc(HID * 4);
    int* bsums    = (int*)alloc(1024 * 4);
    int* boffs    = (int*)alloc(1024 * 4);

    const int L = NB * NBLK;
    int* Hm = (int*)region1;
    int* Sx = Hm + ((L + 63) & ~63);
    __half* h1h = (__half*)region1;              // fp16 rows after build
    unsigned int* tmp = (unsigned int*)region2;
    __half* hrt = (__half*)region2;              // hr fp16 rows after build

    int nb1 = (L + 1023) / 1024;
    hipLaunchKernelGGL(kA_hist, dim3(NBLK), dim3(256), 0, stream, dstA, Hm);
    hipLaunchKernelGGL(k_scan_a, dim3(nb1), dim3(256), 0, stream, Hm, Sx, bsums, L);
    hipLaunchKernelGGL(k_scan_b, dim3(1), dim3(256), 0, stream, bsums, boffs, nb1);
    hipLaunchKernelGGL(k_scan_c, dim3((L + 255) / 256), dim3(256), 0, stream, Sx, boffs, L);
    hipLaunchKernelGGL(kA_scatter, dim3(NBLK), dim3(256), 0, stream, srcA, dstA, Sx, tmp);
    hipLaunchKernelGGL(kB_sort, dim3(NB), dim3(256), 0, stream, tmp, Sx, esrc, rs, deg);

    hipLaunchKernelGGL(k_prep, dim3(1), dim3(64), 0, stream, W2, as2, ad2, va_s, va_d);
    hipLaunchKernelGGL(k_gemm1, dim3(N_NODES / 8), dim3(256), 0, stream, x, W1, as1, ad1, h1h, s1, d1);
    hipLaunchKernelGGL(k_fused1, dim3(N_NODES / 16), dim3(256), 0, stream, rs, deg, esrc,
                       (const uint4*)h1h, s1, d1, b1, va_s, va_d,
                       (uint4*)hrt, s2, d2);
    hipLaunchKernelGGL(k_fused2, dim3(N_NODES / 16), dim3(256), 0, stream, rs, deg, esrc,
                       (const uint4*)hrt, s2, d2, W2, b2, out);
}

// Round 10
// 329.403 us; speedup vs baseline: 1.4395x; 1.0598x over previous
//
#include <hip/hip_runtime.h>
#include <hip/hip_bf16.h>
#include <hip/hip_fp16.h>
#include <math.h>

#define N_NODES 100000
#define N_EDGES 3200000
#define ET (N_EDGES + N_NODES)
#define F_IN 128
#define HID 32
#define NCLS 40
#define NEG 0.2f

// bucket sort geometry
#define NB 782
#define NBLK 782
#define CHUNK 4096
#define BCAP 6144

// ---------------- Pass A: bucket histogram ----------------
__global__ __launch_bounds__(256) void kA_hist(const int* __restrict__ dst,
                                               int* __restrict__ Hm) {
    __shared__ int hist[NB];
    int t = threadIdx.x, k = blockIdx.x;
    for (int i = t; i < NB; i += 256) hist[i] = 0;
    __syncthreads();
    int base = k * CHUNK;
#pragma unroll
    for (int j = 0; j < CHUNK / 256; j++) {
        int e = base + j * 256 + t;
        if (e < N_EDGES) atomicAdd(&hist[dst[e] >> 7], 1);
    }
    __syncthreads();
    for (int i = t; i < NB; i += 256) Hm[i * NBLK + k] = hist[i];
}

// ---------------- generic exclusive scan ----------------
__global__ void k_scan_a(const int* __restrict__ in, int* __restrict__ out,
                         int* __restrict__ bsums, int L) {
    __shared__ int sd[256];
    int t = threadIdx.x, b = blockIdx.x;
    int base = b * 1024 + t * 4;
    int v0 = 0, v1 = 0, v2 = 0, v3 = 0;
    if (base     < L) v0 = in[base];
    if (base + 1 < L) v1 = in[base + 1];
    if (base + 2 < L) v2 = in[base + 2];
    if (base + 3 < L) v3 = in[base + 3];
    int ts = v0 + v1 + v2 + v3;
    sd[t] = ts;
    __syncthreads();
    for (int off = 1; off < 256; off <<= 1) {
        int xx = (t >= off) ? sd[t - off] : 0;
        __syncthreads();
        sd[t] += xx;
        __syncthreads();
    }
    int ex = sd[t] - ts;
    if (t == 255) bsums[b] = sd[255];
    if (base     < L) out[base]     = ex;
    if (base + 1 < L) out[base + 1] = ex + v0;
    if (base + 2 < L) out[base + 2] = ex + v0 + v1;
    if (base + 3 < L) out[base + 3] = ex + v0 + v1 + v2;
}

__global__ void k_scan_b(const int* __restrict__ bsums, int* __restrict__ boffs, int nb) {
    __shared__ int sd[256];
    int t = threadIdx.x;
    int base = t * 4;
    int v0 = 0, v1 = 0, v2 = 0, v3 = 0;
    if (base     < nb) v0 = bsums[base];
    if (base + 1 < nb) v1 = bsums[base + 1];
    if (base + 2 < nb) v2 = bsums[base + 2];
    if (base + 3 < nb) v3 = bsums[base + 3];
    int ts = v0 + v1 + v2 + v3;
    sd[t] = ts;
    __syncthreads();
    for (int off = 1; off < 256; off <<= 1) {
        int xx = (t >= off) ? sd[t - off] : 0;
        __syncthreads();
        sd[t] += xx;
        __syncthreads();
    }
    int ex = sd[t] - ts;
    if (base     < nb) boffs[base]     = ex;
    if (base + 1 < nb) boffs[base + 1] = ex + v0;
    if (base + 2 < nb) boffs[base + 2] = ex + v0 + v1;
    if (base + 3 < nb) boffs[base + 3] = ex + v0 + v1 + v2;
}

__global__ void k_scan_c(int* __restrict__ out, const int* __restrict__ boffs, int L) {
    int i = blockIdx.x * 256 + threadIdx.x;
    if (i < L) out[i] += boffs[i >> 10];
}

// ---------------- Pass A: scatter into buckets ----------------
__global__ __launch_bounds__(256) void kA_scatter(
    const int* __restrict__ src, const int* __restrict__ dst,
    const int* __restrict__ Sx, unsigned int* __restrict__ tmp) {
    __shared__ int hist[NB];
    __shared__ int lofs[NB];
    __shared__ int cur[NB];
    __shared__ int tsum[256];
    __shared__ unsigned int stage[CHUNK];
    __shared__ int gpos[CHUNK];
    int t = threadIdx.x, k = blockIdx.x;
    for (int i = t; i < NB; i += 256) hist[i] = 0;
    __syncthreads();
    int base = k * CHUNK;
    int myd[16], mys[16];
#pragma unroll
    for (int j = 0; j < 16; j++) {
        int e = base + j * 256 + t;
        myd[j] = (e < N_EDGES) ? dst[e] : -1;
        mys[j] = (e < N_EDGES) ? src[e] : 0;
        if (myd[j] >= 0) atomicAdd(&hist[myd[j] >> 7], 1);
    }
    __syncthreads();
    int i0 = 4 * t;
    int h0 = (i0     < NB) ? hist[i0]     : 0;
    int h1 = (i0 + 1 < NB) ? hist[i0 + 1] : 0;
    int h2 = (i0 + 2 < NB) ? hist[i0 + 2] : 0;
    int h3 = (i0 + 3 < NB) ? hist[i0 + 3] : 0;
    int ts = h0 + h1 + h2 + h3;
    tsum[t] = ts;
    __syncthreads();
    for (int off = 1; off < 256; off <<= 1) {
        int xx = (t >= off) ? tsum[t - off] : 0;
        __syncthreads();
        tsum[t] += xx;
        __syncthreads();
    }
    int ex = tsum[t] - ts;
    if (i0     < NB) { lofs[i0]     = ex;                cur[i0]     = 0; }
    if (i0 + 1 < NB) { lofs[i0 + 1] = ex + h0;           cur[i0 + 1] = 0; }
    if (i0 + 2 < NB) { lofs[i0 + 2] = ex + h0 + h1;      cur[i0 + 2] = 0; }
    if (i0 + 3 < NB) { lofs[i0 + 3] = ex + h0 + h1 + h2; cur[i0 + 3] = 0; }
    __syncthreads();
#pragma unroll
    for (int j = 0; j < 16; j++) {
        if (myd[j] >= 0) {
            int bkt = myd[j] >> 7;
            int slot = lofs[bkt] + atomicAdd(&cur[bkt], 1);
            stage[slot] = ((unsigned int)(myd[j] & 127) << 17) | (unsigned int)mys[j];
            gpos[slot] = Sx[bkt * NBLK + k] + (slot - lofs[bkt]);
        }
    }
    __syncthreads();
    int nvalid = min(CHUNK, N_EDGES - base);
    for (int i = t; i < nvalid; i += 256) tmp[gpos[i]] = stage[i];
}

// ---------------- Pass B: per-bucket counting sort ----------------
__global__ __launch_bounds__(256) void kB_sort(
    const unsigned int* __restrict__ tmp, const int* __restrict__ Sx,
    int* __restrict__ esrc, int* __restrict__ rs, int* __restrict__ deg) {
    __shared__ unsigned int stage[BCAP];
    __shared__ int ordered[BCAP + 128];
    __shared__ int cnt[128], lofs[128], cur[128], sc[128];
    int t = threadIdx.x, b = blockIdx.x;
    int myBase = Sx[b * NBLK];
    int nextBase = (b == NB - 1) ? N_EDGES : Sx[(b + 1) * NBLK];
    int cntE = nextBase - myBase;
    int nNodes = min(128, N_NODES - b * 128);
    if (t < 128) { cnt[t] = 0; cur[t] = 0; }
    __syncthreads();
    for (int i = t; i < cntE; i += 256) {
        unsigned int p = tmp[myBase + i];
        stage[i] = p;
        atomicAdd(&cnt[p >> 17], 1);
    }
    __syncthreads();
    int val = 0;
    if (t < 128) { val = (t < nNodes) ? cnt[t] + 1 : 0; sc[t] = val; }
    __syncthreads();
    for (int off = 1; off < 128; off <<= 1) {
        int xx = 0;
        if (t < 128 && t >= off) xx = sc[t - off];
        __syncthreads();
        if (t < 128) sc[t] += xx;
        __syncthreads();
    }
    if (t < 128) lofs[t] = sc[t] - val;
    __syncthreads();
    if (t < nNodes) ordered[lofs[t]] = b * 128 + t;
    for (int i = t; i < cntE; i += 256) {
        unsigned int p = stage[i];
        int n = p >> 17;
        int slot = lofs[n] + 1 + atomicAdd(&cur[n], 1);
        ordered[slot] = (int)(p & 0x1FFFF);
    }
    __syncthreads();
    int gb = myBase + b * 128;
    int totOut = cntE + nNodes;
    for (int i = t; i < totOut; i += 256) esrc[gb + i] = ordered[i];
    if (t < nNodes) {
        rs[b * 128 + t] = gb + lofs[t];
        deg[b * 128 + t] = cnt[t] + 1;
    }
}

// ---------------- prep: va_s = W2 @ att_src2, va_d = W2 @ att_dst2 ----------------
__global__ void k_prep(const float* __restrict__ W2, const float* __restrict__ as2,
                       const float* __restrict__ ad2,
                       float* __restrict__ va_s, float* __restrict__ va_d) {
    int k = threadIdx.x;
    if (k < HID) {
        float ps = 0.f, pd = 0.f;
        for (int c = 0; c < NCLS; c++) {
            float w = W2[k * NCLS + c];
            ps = fmaf(w, as2[c], ps);
            pd = fmaf(w, ad2[c], pd);
        }
        va_s[k] = ps;
        va_d[k] = pd;
    }
}

// ---------------- GEMM1: h1 fp16 rows (64B) ; s1,d1 fp32 ----------------
__global__ __launch_bounds__(256) void k_gemm1(
    const float* __restrict__ x, const float* __restrict__ W1,
    const float* __restrict__ a_s, const float* __restrict__ a_d,
    __half* __restrict__ h1h, float* __restrict__ s1, float* __restrict__ d1) {
    __shared__ float Ws[F_IN * HID];
    __shared__ float xs[8 * F_IN];
    int t = threadIdx.x;
    const float4* W4 = (const float4*)W1;
    float4* Ws4 = (float4*)Ws;
#pragma unroll
    for (int i = 0; i < F_IN * HID / 4 / 256; i++)
        Ws4[t + i * 256] = W4[t + i * 256];
    ((float4*)xs)[t] = ((const float4*)(x + (size_t)blockIdx.x * 8 * F_IN))[t];
    __syncthreads();
    int c = t & 31, g = t >> 5;
    int v = blockIdx.x * 8 + g;
    const float4* xg4 = (const float4*)(xs + g * F_IN);
    float acc = 0.f;
#pragma unroll
    for (int k4 = 0; k4 < F_IN / 4; k4++) {
        float4 xv = xg4[k4];
        int k = k4 * 4;
        acc = fmaf(xv.x, Ws[(k + 0) * HID + c], acc);
        acc = fmaf(xv.y, Ws[(k + 1) * HID + c], acc);
        acc = fmaf(xv.z, Ws[(k + 2) * HID + c], acc);
        acc = fmaf(xv.w, Ws[(k + 3) * HID + c], acc);
    }
    h1h[(size_t)v * HID + c] = __float2half(acc);
    float p = acc * a_s[c];
    float q = acc * a_d[c];
    for (int mm = 16; mm >= 1; mm >>= 1) {
        p += __shfl_xor(p, mm, 32);
        q += __shfl_xor(q, mm, 32);
    }
    if (c == 0) { s1[v] = p; d1[v] = q; }
}

// gather helper: 4-deep pipelined batch over one node's edge segment
#define GATHER_BODY(SARR, TABLE)                                                  \
    float a0 = 0.f, a1 = 0.f, a2 = 0.f, a3 = 0.f,                                 \
          a4 = 0.f, a5 = 0.f, a6 = 0.f, a7 = 0.f;                                 \
    float den = 0.f;                                                              \
    int t = 0;                                                                    \
    for (; t + 16 <= cnt; t += 16) {                                              \
        int p0 = start + t + e;                                                   \
        int sa0 = esrc[p0];                                                       \
        int sa1 = esrc[p0 + 4];                                                   \
        int sa2 = esrc[p0 + 8];                                                   \
        int sa3 = esrc[p0 + 12];                                                  \
        float sv0 = SARR[sa0];                                                    \
        float sv1 = SARR[sa1];                                                    \
        float sv2 = SARR[sa2];                                                    \
        float sv3 = SARR[sa3];                                                    \
        uint4 hv0 = TABLE[(size_t)sa0 * 4 + q];                                   \
        uint4 hv1 = TABLE[(size_t)sa1 * 4 + q];                                   \
        uint4 hv2 = TABLE[(size_t)sa2 * 4 + q];                                   \
        uint4 hv3 = TABLE[(size_t)sa3 * 4 + q];                                   \
        float e0 = sv0 + dval; e0 = (e0 >= 0.f) ? e0 : NEG * e0;                  \
        float e1 = sv1 + dval; e1 = (e1 >= 0.f) ? e1 : NEG * e1;                  \
        float e2 = sv2 + dval; e2 = (e2 >= 0.f) ? e2 : NEG * e2;                  \
        float e3 = sv3 + dval; e3 = (e3 >= 0.f) ? e3 : NEG * e3;                  \
        float w0 = __expf(e0);                                                    \
        float w1 = __expf(e1);                                                    \
        float w2 = __expf(e2);                                                    \
        float w3 = __expf(e3);                                                    \
        den += (w0 + w1) + (w2 + w3);                                             \
        ACC8(w0, hv0); ACC8(w1, hv1); ACC8(w2, hv2); ACC8(w3, hv3);               \
    }                                                                             \
    for (; t < cnt; t += 4) {                                                     \
        int idx = t + e;                                                          \
        int sa = 0;                                                               \
        float w = 0.f;                                                            \
        if (idx < cnt) {                                                          \
            sa = esrc[start + idx];                                               \
            float ev = SARR[sa] + dval;                                           \
            ev = (ev >= 0.f) ? ev : NEG * ev;                                     \
            w = __expf(ev);                                                       \
        }                                                                         \
        uint4 hv = TABLE[(size_t)sa * 4 + q];                                     \
        ACC8(w, hv);                                                              \
        den += w;                                                                 \
    }

#define ACC8(W, HV)                                                               \
    {                                                                             \
        float2 f0 = __half22float2(*(const __half2*)&(HV).x);                     \
        float2 f1 = __half22float2(*(const __half2*)&(HV).y);                     \
        float2 f2 = __half22float2(*(const __half2*)&(HV).z);                     \
        float2 f3 = __half22float2(*(const __half2*)&(HV).w);                     \
        a0 = fmaf((W), f0.x, a0); a1 = fmaf((W), f0.y, a1);                       \
        a2 = fmaf((W), f1.x, a2); a3 = fmaf((W), f1.y, a3);                       \
        a4 = fmaf((W), f2.x, a4); a5 = fmaf((W), f2.y, a5);                       \
        a6 = fmaf((W), f3.x, a6); a7 = fmaf((W), f3.y, a7);                       \
    }

// ---------------- fused layer-1 sweep: 4 nodes/wave, 4-deep pipeline ----------
__global__ __launch_bounds__(256) void k_fused1(
    const int* __restrict__ rs, const int* __restrict__ deg, const int* __restrict__ esrc,
    const uint4* __restrict__ h1r, const float* __restrict__ s1, const float* __restrict__ d1,
    const float* __restrict__ b1, const float* __restrict__ va_s, const float* __restrict__ va_d,
    uint4* __restrict__ hrr, float* __restrict__ s2, float* __restrict__ d2) {
    int tid = threadIdx.x;
    int sub = tid & 15;      // lane within quarter-wave
    int q = sub & 3;         // 16B chunk of the row
    int e = sub >> 2;        // edge slot 0..3
    int v = blockIdx.x * 16 + (tid >> 4);
    int start = rs[v];
    int cnt = deg[v];
    float dval = d1[v];
    GATHER_BODY(s1, h1r)
    // reduce across the 4 edge lanes (bits 2,3)
#pragma unroll
    for (int off = 4; off <= 8; off <<= 1) {
        a0 += __shfl_xor(a0, off); a1 += __shfl_xor(a1, off);
        a2 += __shfl_xor(a2, off); a3 += __shfl_xor(a3, off);
        a4 += __shfl_xor(a4, off); a5 += __shfl_xor(a5, off);
        a6 += __shfl_xor(a6, off); a7 += __shfl_xor(a7, off);
        den += __shfl_xor(den, off);
    }
    if (e == 0) {
        float iden = 1.f / den;
        const float4* b4 = (const float4*)(b1 + q * 8);
        float4 bA = b4[0], bB = b4[1];
        float o0 = fmaxf(a0 * iden + bA.x, 0.f);
        float o1 = fmaxf(a1 * iden + bA.y, 0.f);
        float o2 = fmaxf(a2 * iden + bA.z, 0.f);
        float o3 = fmaxf(a3 * iden + bA.w, 0.f);
        float o4 = fmaxf(a4 * iden + bB.x, 0.f);
        float o5 = fmaxf(a5 * iden + bB.y, 0.f);
        float o6 = fmaxf(a6 * iden + bB.z, 0.f);
        float o7 = fmaxf(a7 * iden + bB.w, 0.f);
        __half2 p0 = __floats2half2_rn(o0, o1);
        __half2 p1 = __floats2half2_rn(o2, o3);
        __half2 p2 = __floats2half2_rn(o4, o5);
        __half2 p3 = __floats2half2_rn(o6, o7);
        uint4 ov;
        ov.x = *(const unsigned int*)&p0;
        ov.y = *(const unsigned int*)&p1;
        ov.z = *(const unsigned int*)&p2;
        ov.w = *(const unsigned int*)&p3;
        hrr[(size_t)v * 4 + q] = ov;
        const float4* vs4 = (const float4*)(va_s + q * 8);
        const float4* vd4 = (const float4*)(va_d + q * 8);
        float4 sA = vs4[0], sB = vs4[1], dA = vd4[0], dB = vd4[1];
        float ps = o0 * sA.x + o1 * sA.y + o2 * sA.z + o3 * sA.w
                 + o4 * sB.x + o5 * sB.y + o6 * sB.z + o7 * sB.w;
        float pd = o0 * dA.x + o1 * dA.y + o2 * dA.z + o3 * dA.w
                 + o4 * dB.x + o5 * dB.y + o6 * dB.z + o7 * dB.w;
        ps += __shfl_xor(ps, 1); pd += __shfl_xor(pd, 1);
        ps += __shfl_xor(ps, 2); pd += __shfl_xor(pd, 2);
        if (q == 0) { s2[v] = ps; d2[v] = pd; }
    }
}

// ---------------- fused layer-2 sweep: 4 nodes/wave, 4-deep + @W2 + log_softmax ----
__global__ __launch_bounds__(256) void k_fused2(
    const int* __restrict__ rs, const int* __restrict__ deg, const int* __restrict__ esrc,
    const uint4* __restrict__ hrr, const float* __restrict__ s2, const float* __restrict__ d2,
    const float* __restrict__ W2, const float* __restrict__ b2, float* __restrict__ out) {
    __shared__ float W2s[HID * NCLS];     // 5 KB
    __shared__ float hragg[16][HID];      // 2 KB
    __shared__ float zbuf[16][NCLS];      // 2.5 KB
    __shared__ float gm[16], gl[16];
    int tid = threadIdx.x;
    for (int i = tid; i < HID * NCLS; i += 256) W2s[i] = W2[i];
    int sub = tid & 15;
    int q = sub & 3;
    int e = sub >> 2;
    int node = tid >> 4;               // 0..15 within block
    int v = blockIdx.x * 16 + node;
    int start = rs[v];
    int cnt = deg[v];
    float dval = d2[v];
    GATHER_BODY(s2, hrr)
#pragma unroll
    for (int off = 4; off <= 8; off <<= 1) {
        a0 += __shfl_xor(a0, off); a1 += __shfl_xor(a1, off);
        a2 += __shfl_xor(a2, off); a3 += __shfl_xor(a3, off);
        a4 += __shfl_xor(a4, off); a5 += __shfl_xor(a5, off);
        a6 += __shfl_xor(a6, off); a7 += __shfl_xor(a7, off);
        den += __shfl_xor(den, off);
    }
    if (e == 0) {
        float iden = 1.f / den;
        int cb = q * 8;
        hragg[node][cb + 0] = a0 * iden;
        hragg[node][cb + 1] = a1 * iden;
        hragg[node][cb + 2] = a2 * iden;
        hragg[node][cb + 3] = a3 * iden;
        hragg[node][cb + 4] = a4 * iden;
        hragg[node][cb + 5] = a5 * iden;
        hragg[node][cb + 6] = a6 * iden;
        hragg[node][cb + 7] = a7 * iden;
    }
    __syncthreads();
    // z = hragg @ W2 + b2, relu — 640 outputs over 256 threads
    for (int oi = tid; oi < 16 * NCLS; oi += 256) {
        int n = oi / NCLS, c = oi % NCLS;
        float z = 0.f;
#pragma unroll
        for (int k = 0; k < HID; k++)
            z = fmaf(hragg[n][k], W2s[k * NCLS + c], z);
        zbuf[n][c] = fmaxf(z + b2[c], 0.f);
    }
    __syncthreads();
    if (tid < 16) {
        float mx = -INFINITY;
        for (int c = 0; c < NCLS; c++) mx = fmaxf(mx, zbuf[tid][c]);
        float se = 0.f;
        for (int c = 0; c < NCLS; c++) se += __expf(zbuf[tid][c] - mx);
        gm[tid] = mx;
        gl[tid] = logf(se);
    }
    __syncthreads();
    for (int oi = tid; oi < 16 * NCLS; oi += 256) {
        int n = oi / NCLS, c = oi % NCLS;
        out[(size_t)(blockIdx.x * 16 + n) * NCLS + c] = zbuf[n][c] - gm[n] - gl[n];
    }
}

// ---------------- launch ----------------

extern "C" void kernel_launch(void* const* d_in, const int* in_sizes, int n_in,
                              void* d_out, int out_size, void* d_ws, size_t ws_size,
                              hipStream_t stream) {
    (void)in_sizes; (void)n_in; (void)out_size; (void)ws_size;
    const float* x   = (const float*)d_in[0];
    const int*   ei  = (const int*)d_in[1];
    const float* W1  = (const float*)d_in[2];
    const float* as1 = (const float*)d_in[3];
    const float* ad1 = (const float*)d_in[4];
    const float* b1  = (const float*)d_in[5];
    const float* W2  = (const float*)d_in[6];
    const float* as2 = (const float*)d_in[7];
    const float* ad2 = (const float*)d_in[8];
    const float* b2  = (const float*)d_in[9];
    float* out = (float*)d_out;
    const int* srcA = ei;
    const int* dstA = ei + N_EDGES;

    char* w = (char*)d_ws;
    size_t off = 0;
    auto alloc = [&](size_t bytes) {
        char* p = w + off;
        off = (off + bytes + 255) & ~(size_t)255;
        return p;
    };
    int* esrc     = (int*)alloc((size_t)ET * 4);
    int* rs       = (int*)alloc((size_t)N_NODES * 4);
    int* deg      = (int*)alloc((size_t)N_NODES * 4);
    char* region1 = alloc((size_t)N_NODES * HID * 4);   // Hm/Sx during build, then h1h (6.4MB)
    float* s1     = (float*)alloc((size_t)N_NODES * 4);
    float* d1     = (float*)alloc((size_t)N_NODES * 4);
    char* region2 = alloc((size_t)N_EDGES * 4 + 1024);  // tmp during build, then hrt (6.4MB)
    float* s2     = (float*)alloc((size_t)N_NODES * 4);
    float* d2     = (float*)alloc((size_t)N_NODES * 4);
    float* va_s   = (float*)alloc(HID * 4);
    float* va_d   = (float*)alloc(HID * 4);
    int* bsums    = (int*)alloc(1024 * 4);
    int* boffs    = (int*)alloc(1024 * 4);

    const int L = NB * NBLK;
    int* Hm = (int*)region1;
    int* Sx = Hm + ((L + 63) & ~63);
    __half* h1h = (__half*)region1;              // fp16 rows after build
    unsigned int* tmp = (unsigned int*)region2;
    __half* hrt = (__half*)region2;              // hr fp16 rows after build

    int nb1 = (L + 1023) / 1024;
    hipLaunchKernelGGL(kA_hist, dim3(NBLK), dim3(256), 0, stream, dstA, Hm);
    hipLaunchKernelGGL(k_scan_a, dim3(nb1), dim3(256), 0, stream, Hm, Sx, bsums, L);
    hipLaunchKernelGGL(k_scan_b, dim3(1), dim3(256), 0, stream, bsums, boffs, nb1);
    hipLaunchKernelGGL(k_scan_c, dim3((L + 255) / 256), dim3(256), 0, stream, Sx, boffs, L);
    hipLaunchKernelGGL(kA_scatter, dim3(NBLK), dim3(256), 0, stream, srcA, dstA, Sx, tmp);
    hipLaunchKernelGGL(kB_sort, dim3(NB), dim3(256), 0, stream, tmp, Sx, esrc, rs, deg);

    hipLaunchKernelGGL(k_prep, dim3(1), dim3(64), 0, stream, W2, as2, ad2, va_s, va_d);
    hipLaunchKernelGGL(k_gemm1, dim3(N_NODES / 8), dim3(256), 0, stream, x, W1, as1, ad1, h1h, s1, d1);
    hipLaunchKernelGGL(k_fused1, dim3(N_NODES / 16), dim3(256), 0, stream, rs, deg, esrc,
                       (const uint4*)h1h, s1, d1, b1, va_s, va_d,
                       (uint4*)hrt, s2, d2);
    hipLaunchKernelGGL(k_fused2, dim3(N_NODES / 16), dim3(256), 0, stream, rs, deg, esrc,
                       (const uint4*)hrt, s2, d2, W2, b2, out);
}